// Round 8
// baseline (544.589 us; speedup 1.0000x reference)
//
#include <hip/hip_runtime.h>
#include <math.h>

#define COMMITMENT_COST 0.25f
#define DECAY 0.99f
#define EPSILON 1e-05f
#define KCODES 1024
#define DIM 256
#define NTOK 32768

// out-buffer float offsets (concatenated return tuple)
#define O_QUANT 0
#define O_LOSS  8388608
#define O_IDX   8388609
#define O_CS    8421377
#define O_EMAW  8422401
#define O_EMB   8684545

// scratch in the new_embedding slot (262144 floats, written LAST by fin2).
// O_EMB is odd -> +1 float makes packed u64 8-byte aligned.
#define SE_PACKED 1        // u64 x 32768 -> floats [1, 65537)
#define SE_ESQ    65544
#define SE_ZSQ    66568    // 32768 floats
#define SE_HIST   99336    // 1024 ints
#define SE_NM     100360   // 1 int: multi-survivor token count
#define SE_NOVF   100361   // 1 int: overflow-token count
#define SE_OVF    100362   // 32768 ints -> ends 133130
#define SE_OFFS   133136   // 1025 ints
#define SE_CUR    134168   // 1024 ints
#define SE_TLIST  135200   // 32768 ints -> ends 167968
#define SE_MLIST  167968   // 32768 ints -> ends 200736 < 262144

// scratch in the O_QUANT slot (8388608 floats, written by mid AFTER recheck).
// All consumers (dist_mfma, recheck_a/b) run before mid.
#define SQ_ZH    0         // ushort[32768*256] -> floats [0, 4194304)
#define SQ_EH    4194304   // ushort[1024*256]  -> floats [4194304, 4325376)
#define SQ_MG    4325376   // u64[32768]        -> floats [4325376, 4390912)
#define SQ_CC    4390912   // int[32768]        -> floats [4390912, 4423680)
#define SQ_CAND  4423680   // u64[56][32768] TRANSPOSED -> floats [4423680, 8093696)

// exact-argmin recovery thresholds (rounds 1-6 validated: zero flips).
#define THETA 0.012f
#define THETA_F 0.008f
#define CAND_CAP 56
// fp32 summation-order bound: products |z_i*e_i| <= ~0.006, partial sums
// <= 0.31 -> per-ordering acc error <= 256 * 0.5ulp(0.31) ~ 4e-6; x2 for
// 2*acc, + final-subtract rounding 2*0.5ulp(360) ~ 4.4e-5 -> |dv_serial -
// dv_parallel| <= ~6e-5. EPSC = 2e-4 gives >3x safety margin.
#define EPSC 2e-4f

typedef __attribute__((ext_vector_type(8))) short bf16x8;
typedef __attribute__((ext_vector_type(4))) float f32x4;

__device__ __forceinline__ unsigned short f2bf(float x) {
    unsigned u = __float_as_uint(x);
    return (unsigned short)((u + 0x7FFFu + ((u >> 16) & 1u)) >> 16);  // RNE
}
__device__ __forceinline__ unsigned mono(float f) {   // order-preserving f32->u32
    unsigned u = __float_as_uint(f);
    return u ^ ((u & 0x80000000u) ? 0xFFFFFFFFu : 0x80000000u);
}
__device__ __forceinline__ float invmono(unsigned m) {
    unsigned u = m ^ ((m & 0x80000000u) ? 0x80000000u : 0xFFFFFFFFu);
    return __uint_as_float(u);
}

// ------- pre: zsq/esq, bf16 casts zh/eh, zero hist/loss/counters, init -------
__global__ void pre_kernel(const float* __restrict__ z, const float* __restrict__ E,
                           float* __restrict__ zsq, float* __restrict__ esq,
                           int* __restrict__ hist,
                           unsigned long long* __restrict__ packed,
                           float* __restrict__ loss,
                           unsigned short* __restrict__ zh,
                           unsigned short* __restrict__ eh,
                           int* __restrict__ nm, int* __restrict__ novf) {
    const int b = blockIdx.x;
    const int wave = threadIdx.x >> 6;
    const int lane = threadIdx.x & 63;
    if (b < NTOK / 4) {
        int token = b * 4 + wave;
        float4 v = ((const float4*)(z + (size_t)token * DIM))[lane];
        ushort4 h;
        h.x = f2bf(v.x); h.y = f2bf(v.y); h.z = f2bf(v.z); h.w = f2bf(v.w);
        *(ushort4*)(zh + (size_t)token * DIM + lane * 4) = h;
        float s = v.x * v.x + v.y * v.y + v.z * v.z + v.w * v.w;
        #pragma unroll
        for (int off = 32; off > 0; off >>= 1) s += __shfl_down(s, off);
        if (lane == 0) zsq[token] = s;
        if (threadIdx.x < 4) packed[b * 4 + threadIdx.x] = ~0ull;
        if (b == 0 && threadIdx.x == 4) loss[0] = 0.0f;
        if (b == 0 && threadIdx.x == 5) { *nm = 0; *novf = 0; }
    } else {
        int eb = b - NTOK / 4;                 // 0..255
        int k = eb * 4 + wave;
        float4 v = ((const float4*)(E + (size_t)k * DIM))[lane];
        ushort4 h;
        h.x = f2bf(v.x); h.y = f2bf(v.y); h.z = f2bf(v.z); h.w = f2bf(v.w);
        *(ushort4*)(eh + (size_t)k * DIM + lane * 4) = h;
        float s = v.x * v.x + v.y * v.y + v.z * v.z + v.w * v.w;
        #pragma unroll
        for (int off = 32; off > 0; off >>= 1) s += __shfl_down(s, off);
        if (lane == 0) esq[k] = s;
        if (threadIdx.x < 4) hist[eb * 4 + threadIdx.x] = 0;
    }
}

// ---------------- bf16 MFMA approximate-distance pass (token-owner) ----------
// One block OWNS 64 tokens: loops all 8 code-chunks with a running min.
// A (64x256 zh tile) staged in LDS once; B (128x32 eh chunk) staged per kt.
// Emission: d <= runmin_after_chunk + THETA (monotone tightening, ~13/token).
__global__ __launch_bounds__(256) void dist_mfma_kernel(
        const unsigned short* __restrict__ zh, const unsigned short* __restrict__ eh,
        const float* __restrict__ esq,
        unsigned long long* __restrict__ Mg, int* __restrict__ ccount,
        unsigned long long* __restrict__ cand) {
    __shared__ unsigned short Als[64 * 264];   // 33792 us, row 528B (16B-mult)
    __shared__ unsigned short Bls[128 * 40];   // 10240 us
    __shared__ float scr[64][4];
    __shared__ float runmin[64];
    __shared__ int lcnt[64];

    const int tid = threadIdx.x;
    const int wn = tid >> 6;                 // wave -> 32-col quarter
    const int lane = tid & 63;
    const int l15 = lane & 15, l4 = lane >> 4;
    const int tok0 = blockIdx.x * 64;

    // stage A once: 64 rows x 256 cols = 2048 bf16x8 chunks, 8 per thread
    #pragma unroll
    for (int q = 0; q < 8; ++q) {
        int c = tid + 256 * q;               // 0..2047
        int row = c >> 5, ch = c & 31;
        *(bf16x8*)(Als + row * 264 + ch * 8) =
            *(const bf16x8*)(zh + (size_t)(tok0 + row) * 256 + ch * 8);
    }
    if (tid < 64) { runmin[tid] = 3.4e38f; lcnt[tid] = 0; }
    __syncthreads();

    const int brow0 = tid >> 2, bch = tid & 3;   // B staging coords

    for (int c0 = 0; c0 < KCODES; c0 += 128) {
        f32x4 acc[4][2];
        #pragma unroll
        for (int i = 0; i < 4; ++i)
            #pragma unroll
            for (int j = 0; j < 2; ++j)
                acc[i][j] = (f32x4){0.f, 0.f, 0.f, 0.f};

        for (int kt = 0; kt < 8; ++kt) {
            const int kk = kt * 32;
            bf16x8 b0 = *(const bf16x8*)(
                eh + (size_t)(c0 + brow0) * 256 + kk + bch * 8);
            bf16x8 b1 = *(const bf16x8*)(
                eh + (size_t)(c0 + brow0 + 64) * 256 + kk + bch * 8);
            __syncthreads();                 // prior Bls reads / emits done
            *(bf16x8*)(Bls + brow0 * 40 + bch * 8) = b0;
            *(bf16x8*)(Bls + (brow0 + 64) * 40 + bch * 8) = b1;
            __syncthreads();
            bf16x8 av[4], bv[2];
            #pragma unroll
            for (int i = 0; i < 4; ++i)
                av[i] = *(const bf16x8*)(Als + (i * 16 + l15) * 264 + kk + l4 * 8);
            #pragma unroll
            for (int j = 0; j < 2; ++j)
                bv[j] = *(const bf16x8*)(Bls + (wn * 32 + j * 16 + l15) * 40 + l4 * 8);
            #pragma unroll
            for (int i = 0; i < 4; ++i)
                #pragma unroll
                for (int j = 0; j < 2; ++j)
                    acc[i][j] = __builtin_amdgcn_mfma_f32_16x16x32_bf16(
                        av[i], bv[j], acc[i][j], 0, 0, 0);
        }

        float sq[2];
        #pragma unroll
        for (int j = 0; j < 2; ++j) sq[j] = esq[c0 + wn * 32 + j * 16 + l15];

        #pragma unroll
        for (int i = 0; i < 4; ++i) {
            #pragma unroll
            for (int r = 0; r < 4; ++r) {
                float v = fminf(sq[0] - 2.0f * acc[i][0][r],
                                sq[1] - 2.0f * acc[i][1][r]);
                #pragma unroll
                for (int m = 1; m < 16; m <<= 1)
                    v = fminf(v, __shfl_xor(v, m));
                if (l15 == 0) scr[i * 16 + l4 * 4 + r][wn] = v;
            }
        }
        __syncthreads();
        if (tid < 64) {
            float m = fminf(fminf(scr[tid][0], scr[tid][1]),
                            fminf(scr[tid][2], scr[tid][3]));
            runmin[tid] = fminf(runmin[tid], m);
        }
        __syncthreads();
        #pragma unroll
        for (int i = 0; i < 4; ++i) {
            #pragma unroll
            for (int r = 0; r < 4; ++r) {
                const int row = i * 16 + l4 * 4 + r;
                const float thr = runmin[row] + THETA;
                #pragma unroll
                for (int j = 0; j < 2; ++j) {
                    float d = sq[j] - 2.0f * acc[i][j][r];
                    if (d <= thr) {
                        int slot = atomicAdd(&lcnt[row], 1);
                        if (slot < CAND_CAP)
                            cand[(size_t)slot * NTOK + tok0 + row] =
                                (((unsigned long long)__float_as_uint(d)) << 32) |
                                (unsigned)(c0 + wn * 32 + j * 16 + l15);
                    }
                }
            }
        }
    }
    __syncthreads();    // all emits / lcnt atomics done
    if (tid < 64) {
        Mg[tok0 + tid] = ((unsigned long long)mono(runmin[tid])) << 32;
        ccount[tok0 + tid] = lcnt[tid];
    }
}

// ------- recheck_a: per-TOKEN filter at THETA_F; 1 survivor -> direct write;
// >=2 -> mlist (wave-coalesced atomic); overflow/paranoia -> ovf list. -------
__global__ __launch_bounds__(256) void recheck_a_kernel(
        const unsigned long long* __restrict__ Mg, const int* __restrict__ ccount,
        const unsigned long long* __restrict__ cand,
        unsigned long long* __restrict__ packed,
        int* __restrict__ mlist, int* __restrict__ nm,
        int* __restrict__ ovf, int* __restrict__ novf) {
    const int token = blockIdx.x * 256 + threadIdx.x;
    const int cnt = ccount[token];
    const float thr = invmono((unsigned)(Mg[token] >> 32)) + THETA_F;

    if (cnt > CAND_CAP) {
        int s = atomicAdd(novf, 1);
        ovf[s] = token;
        return;
    }
    int nsurv = 0;
    int firstcode = 0;
    for (int s = 0; s < cnt; ++s) {
        unsigned long long e = cand[(size_t)s * NTOK + token];
        float dt = __uint_as_float((unsigned)(e >> 32));
        if (dt <= thr) {
            ++nsurv;
            if (nsurv == 1) firstcode = (int)(unsigned)(e & 0x3FFull);
        }
    }
    if (nsurv == 1) {
        packed[token] = (unsigned long long)(unsigned)firstcode;  // low32 = idx
    } else if (nsurv >= 2) {
        int m = atomicAdd(nm, 1);
        mlist[m] = token;
    } else {
        int s = atomicAdd(novf, 1);   // nsurv==0: impossible, safety net
        ovf[s] = token;
    }
}

// ------- recheck_b: wave per multi-survivor token ----------
// Coalesced z-row + per-survivor coalesced E-row; wave-parallel fp32 dot
// (butterfly reduce). Certified gate: if min2-min1 > 2*EPSC the serial-order
// argmin provably equals the parallel argmin (|dv_serial - dv_par| <= EPSC
// per pair) -> write index directly. Else (rare ~3-5%, incl. exact ties):
// lane-0 bit-exact serial chain per survivor with first-index tie-break.
#define RB_BLOCKS 1024
__global__ __launch_bounds__(256) void recheck_b_kernel(
        const float* __restrict__ z, const float* __restrict__ E,
        const float* __restrict__ zsq, const float* __restrict__ esq,
        const unsigned long long* __restrict__ Mg, const int* __restrict__ ccount,
        const unsigned long long* __restrict__ cand,
        const int* __restrict__ mlist, const int* __restrict__ nm,
        const int* __restrict__ ovf, const int* __restrict__ novf,
        unsigned long long* __restrict__ packed) {
    const int wave = threadIdx.x >> 6, lane = threadIdx.x & 63;
    const int gw = blockIdx.x * 4 + wave;
    const int n = *nm;
    for (int m = gw; m < n; m += RB_BLOCKS * 4) {
        const int token = mlist[m];
        const int cnt = ccount[token];         // <= CAND_CAP <= 64
        const float thr = invmono((unsigned)(Mg[token] >> 32)) + THETA_F;
        const float An = zsq[token];
        const float4 zv = *(const float4*)(z + (size_t)token * DIM + lane * 4);
        unsigned long long e = 0xFFFFFFFF00000000ull;   // dt = NaN -> filtered
        if (lane < cnt) e = cand[(size_t)lane * NTOK + token];
        const float dt = __uint_as_float((unsigned)(e >> 32));
        const int ec = (int)(unsigned)(e & 0x3FFull);
        const unsigned long long bm0 = __ballot(lane < cnt && dt <= thr);

        unsigned long long bm = bm0;
        float m1 = 3.4e38f, m2 = 3.4e38f; int a1 = 0x7fffffff;
        while (bm) {
            const int s = __ffsll(bm) - 1; bm &= bm - 1;
            const int code = __shfl(ec, s);
            const float4 ev = *(const float4*)(E + (size_t)code * DIM + lane * 4);
            float p = fmaf(zv.x, ev.x, 0.0f);
            p = fmaf(zv.y, ev.y, p);
            p = fmaf(zv.z, ev.z, p);
            p = fmaf(zv.w, ev.w, p);
            #pragma unroll
            for (int o = 1; o < 64; o <<= 1) p += __shfl_xor(p, o);
            const float dv = (An + esq[code]) - 2.0f * p;
            if (dv < m1 || (dv == m1 && code < a1)) { m2 = m1; m1 = dv; a1 = code; }
            else if (dv < m2) m2 = dv;
        }
        if (m2 - m1 > 2.0f * EPSC) {
            if (lane == 0) packed[token] = (unsigned long long)(unsigned)a1;
        } else {
            // bit-exact fallback: serial fmaf chain (reference order) per surv
            unsigned long long bb = bm0;
            float b1 = 3.4e38f; int ai = 0x7fffffff;
            while (bb) {
                const int s = __ffsll(bb) - 1; bb &= bb - 1;
                const int code = __shfl(ec, s);
                if (lane == 0) {
                    const float4* zp = (const float4*)(z + (size_t)token * DIM);
                    const float4* ep = (const float4*)(E + (size_t)code * DIM);
                    float acc = 0.0f;
                    #pragma unroll 8
                    for (int q = 0; q < 64; ++q) {
                        float4 a = zp[q], b = ep[q];
                        acc = fmaf(a.x, b.x, acc); acc = fmaf(a.y, b.y, acc);
                        acc = fmaf(a.z, b.z, acc); acc = fmaf(a.w, b.w, acc);
                    }
                    float dv = (An + esq[code]) - 2.0f * acc;
                    if (dv < b1 || (dv == b1 && code < ai)) { b1 = dv; ai = code; }
                }
            }
            if (lane == 0) packed[token] = (unsigned long long)(unsigned)ai;
        }
    }
    // overflow tokens (expected 0): wave-per-token full exact scan
    const int nov = *novf;
    for (int w = gw; w < nov; w += RB_BLOCKS * 4) {
        const int token = ovf[w];
        const float An = zsq[token];
        const float4* zp = (const float4*)(z + (size_t)token * DIM);
        float best = 3.4e38f; int bid = 0x7fffffff;
        for (int code = lane; code < KCODES; code += 64) {
            const float4* ep = (const float4*)(E + (size_t)code * DIM);
            float acc = 0.0f;
            for (int q = 0; q < 64; ++q) {
                float4 a = zp[q], b = ep[q];
                acc = fmaf(a.x, b.x, acc); acc = fmaf(a.y, b.y, acc);
                acc = fmaf(a.z, b.z, acc); acc = fmaf(a.w, b.w, acc);
            }
            float dv = (An + esq[code]) - 2.0f * acc;
            if (dv < best || (dv == best && code < bid)) { best = dv; bid = code; }
        }
        #pragma unroll
        for (int mm = 1; mm < 64; mm <<= 1) {
            float ov = __shfl_xor(best, mm); int oi = __shfl_xor(bid, mm);
            if (ov < best || (ov == best && oi < bid)) { best = ov; bid = oi; }
        }
        if (lane == 0)
            packed[token] = (((unsigned long long)__float_as_uint(best)) << 32) |
                            (unsigned)bid;
    }
}

// ------- mid: unpack idx, hist, quant gather, loss (NO dw atomics) -------
__global__ __launch_bounds__(256) void mid_kernel(
        const float* __restrict__ z, const float* __restrict__ E,
        const unsigned long long* __restrict__ packed,
        float* __restrict__ idx_out, int* __restrict__ hist,
        float* __restrict__ quant, float* __restrict__ loss_acc) {
    __shared__ float ls[4];
    const int wave = threadIdx.x >> 6;
    const int lane = threadIdx.x & 63;
    const int token = blockIdx.x * 4 + wave;
    const int idx = (int)(unsigned)(packed[token] & 0x3FFull);

    if (lane == 0) {
        idx_out[token] = (float)idx;
        atomicAdd(&hist[idx], 1);
    }

    const float4 ev = *(const float4*)(E + (size_t)idx * DIM + lane * 4);
    const float4 zv = *(const float4*)(z + (size_t)token * DIM + lane * 4);
    *(float4*)(quant + (size_t)token * DIM + lane * 4) = ev;

    float dx = zv.x - ev.x, dy = zv.y - ev.y, dz = zv.z - ev.z, dww = zv.w - ev.w;
    float l = dx * dx + dy * dy + dz * dz + dww * dww;
    #pragma unroll
    for (int off = 32; off > 0; off >>= 1) l += __shfl_down(l, off);
    if (lane == 0) ls[wave] = l;
    __syncthreads();
    if (threadIdx.x == 0)
        atomicAdd(loss_acc, ls[0] + ls[1] + ls[2] + ls[3]);
}

// ------- cs: cluster-size normalize + hist prefix-sum (offs/cursor) -------
__global__ __launch_bounds__(256) void cs_kernel(
        const int* __restrict__ hist, const float* __restrict__ ema_cs,
        float* __restrict__ cs_out, int* __restrict__ offs,
        int* __restrict__ cursor) {
    __shared__ float f[256];
    __shared__ int hs[256];
    const int tid = threadIdx.x;
    float pre4[4]; int h4[4];
    float part = 0.0f; int hp = 0;
    #pragma unroll
    for (int q = 0; q < 4; ++q) {
        int k = tid * 4 + q;
        h4[q] = hist[k];
        pre4[q] = ema_cs[k] * DECAY + (1.0f - DECAY) * (float)h4[q];
        part += pre4[q];
        hp += h4[q];
    }
    f[tid] = part; hs[tid] = hp;
    __syncthreads();
    #pragma unroll
    for (int off = 1; off < 256; off <<= 1) {
        int v = (tid >= off) ? hs[tid - off] : 0;
        __syncthreads();
        hs[tid] += v;
        __syncthreads();
    }
    int run = hs[tid] - hp;                 // exclusive base for this thread
    #pragma unroll
    for (int q = 0; q < 4; ++q) {
        int k = tid * 4 + q;
        offs[k] = run; cursor[k] = run;
        run += h4[q];
    }
    if (tid == 255) offs[KCODES] = run;     // = NTOK
    for (int s = 128; s > 0; s >>= 1) {
        if (tid < s) f[tid] += f[tid + s];
        __syncthreads();
    }
    float n = f[0];
    #pragma unroll
    for (int q = 0; q < 4; ++q) {
        int k = tid * 4 + q;
        cs_out[k] = (pre4[q] + EPSILON) / (n + KCODES * EPSILON) * n;
    }
}

// ------- scatter: counting-sort tokens into per-code buckets -------
__global__ __launch_bounds__(256) void scatter_kernel(
        const unsigned long long* __restrict__ packed,
        int* __restrict__ cursor, int* __restrict__ tlist) {
    const int t = blockIdx.x * 256 + threadIdx.x;
    const int idx = (int)(unsigned)(packed[t] & 0x3FFull);
    const int pos = atomicAdd(&cursor[idx], 1);
    tlist[pos] = t;
}

// ------- fin_gather: dw[k] = sum of z rows assigned to code k -------
__global__ __launch_bounds__(256) void fin_gather_kernel(
        const float* __restrict__ z, const int* __restrict__ offs,
        const int* __restrict__ tlist, float* __restrict__ dw) {
    __shared__ float4 red[4][64];
    const int k = blockIdx.x;
    const int grp = threadIdx.x >> 6;
    const int lane = threadIdx.x & 63;
    const int s = offs[k], e = offs[k + 1];
    float4 acc = {0.f, 0.f, 0.f, 0.f};
    for (int i = s + grp; i < e; i += 4) {
        const int t = tlist[i];
        const float4 v = *(const float4*)(z + (size_t)t * DIM + lane * 4);
        acc.x += v.x; acc.y += v.y; acc.z += v.z; acc.w += v.w;
    }
    red[grp][lane] = acc;
    __syncthreads();
    if (grp == 0) {
        float4 a = red[0][lane], b = red[1][lane];
        float4 c = red[2][lane], d = red[3][lane];
        float4 o;
        o.x = (a.x + b.x) + (c.x + d.x);
        o.y = (a.y + b.y) + (c.y + d.y);
        o.z = (a.z + b.z) + (c.z + d.z);
        o.w = (a.w + b.w) + (c.w + d.w);
        *(float4*)(dw + (size_t)k * DIM + lane * 4) = o;
    }
}

// ------- fin2: new_ema_w & new_embedding (+ loss finalize) -------
__global__ __launch_bounds__(256) void fin_kernel(
        const float* __restrict__ ema_w, const float* __restrict__ cs,
        float* __restrict__ emaw_inout /* holds dw */, float* __restrict__ emb_out,
        float* __restrict__ loss_inout) {
    const int i = blockIdx.x * 256 + threadIdx.x;   // f4 index, 65536 total
    const int k = i >> 6;
    float4 d = ((const float4*)emaw_inout)[i];
    float4 w = ((const float4*)ema_w)[i];
    float4 nw;
    nw.x = w.x * DECAY + (1.0f - DECAY) * d.x;
    nw.y = w.y * DECAY + (1.0f - DECAY) * d.y;
    nw.z = w.z * DECAY + (1.0f - DECAY) * d.z;
    nw.w = w.w * DECAY + (1.0f - DECAY) * d.w;
    ((float4*)emaw_inout)[i] = nw;
    float inv = 1.0f / cs[k];
    float4 e; e.x = nw.x * inv; e.y = nw.y * inv; e.z = nw.z * inv; e.w = nw.w * inv;
    ((float4*)emb_out)[i] = e;
    if (i == 0)
        loss_inout[0] = COMMITMENT_COST * loss_inout[0] / (float)((size_t)NTOK * DIM);
}

extern "C" void kernel_launch(void* const* d_in, const int* in_sizes, int n_in,
                              void* d_out, int out_size, void* d_ws, size_t ws_size,
                              hipStream_t stream) {
    const float* z      = (const float*)d_in[0];
    const float* E      = (const float*)d_in[1];
    const float* ema_cs = (const float*)d_in[2];
    const float* ema_w  = (const float*)d_in[3];
    float* out = (float*)d_out;

    float* emb = out + O_EMB;
    unsigned long long* packed = (unsigned long long*)(emb + SE_PACKED);
    float* esq  = emb + SE_ESQ;
    float* zsq  = emb + SE_ZSQ;
    int*   hist = (int*)(emb + SE_HIST);
    int*   nm     = (int*)(emb + SE_NM);
    int*   novf   = (int*)(emb + SE_NOVF);
    int*   ovf    = (int*)(emb + SE_OVF);
    int*   offs   = (int*)(emb + SE_OFFS);
    int*   cursor = (int*)(emb + SE_CUR);
    int*   tlist  = (int*)(emb + SE_TLIST);
    int*   mlist  = (int*)(emb + SE_MLIST);

    unsigned short* zh = (unsigned short*)(out + SQ_ZH);
    unsigned short* eh = (unsigned short*)(out + SQ_EH);
    unsigned long long* Mg = (unsigned long long*)(out + SQ_MG);
    int* ccount = (int*)(out + SQ_CC);
    unsigned long long* cand = (unsigned long long*)(out + SQ_CAND);

    pre_kernel<<<NTOK / 4 + KCODES / 4, 256, 0, stream>>>(
        z, E, zsq, esq, hist, packed, out + O_LOSS, zh, eh, nm, novf);
    dist_mfma_kernel<<<NTOK / 64, 256, 0, stream>>>(
        zh, eh, esq, Mg, ccount, cand);
    recheck_a_kernel<<<NTOK / 256, 256, 0, stream>>>(
        Mg, ccount, cand, packed, mlist, nm, ovf, novf);
    recheck_b_kernel<<<RB_BLOCKS, 256, 0, stream>>>(
        z, E, zsq, esq, Mg, ccount, cand, mlist, nm, ovf, novf, packed);
    mid_kernel<<<NTOK / 4, 256, 0, stream>>>(z, E, packed, out + O_IDX, hist,
                                             out + O_QUANT, out + O_LOSS);
    cs_kernel<<<1, 256, 0, stream>>>(hist, ema_cs, out + O_CS, offs, cursor);
    scatter_kernel<<<NTOK / 256, 256, 0, stream>>>(packed, cursor, tlist);
    fin_gather_kernel<<<KCODES, 256, 0, stream>>>(z, offs, tlist, out + O_EMAW);
    fin_kernel<<<256, 256, 0, stream>>>(ema_w, out + O_CS, out + O_EMAW, emb,
                                        out + O_LOSS);
}

// Round 9
// 335.679 us; speedup vs baseline: 1.6224x; 1.6224x over previous
//
#include <hip/hip_runtime.h>
#include <hip/hip_fp16.h>
#include <math.h>

#define COMMITMENT_COST 0.25f
#define DECAY 0.99f
#define EPSILON 1e-05f
#define KCODES 1024
#define DIM 256
#define NTOK 32768

// out-buffer float offsets (concatenated return tuple)
#define O_QUANT 0
#define O_LOSS  8388608
#define O_IDX   8388609
#define O_CS    8421377
#define O_EMAW  8422401
#define O_EMB   8684545

// scratch in the new_embedding slot (262144 floats, written LAST by fin).
// No u64 here -> no 8B-alignment concern (O_EMB odd is fine for int/float).
#define SE_IDX    0        // u32[32768]: final code per token
#define SE_ESQ    32768    // f32[1024]
#define SE_ZSQ    33792    // f32[32768]
#define SE_HIST   66560    // int[1024]
#define SE_NM     67584    // int
#define SE_NOVF   67585    // int
#define SE_MLIST  67586    // int[32768]
#define SE_OVF    100354   // int[32768]
#define SE_OFFS   133122   // int[1025]
#define SE_CUR    134147   // int[1024]
#define SE_TLIST  135171   // int[32768] -> ends 167939 < 262144

// scratch in the O_QUANT slot (8388608 floats, written by mid AFTER recheck).
#define SQ_ZH    0         // f16[32768*256] -> floats [0, 4194304)
#define SQ_EH    4194304   // f16[1024*256]  -> floats [4194304, 4325376)
#define SQ_MG    4325376   // f32[32768]
#define SQ_CC    4358144   // int[32768]
#define SQ_CAND  4390912   // u64[16][32768] TRANSPOSED -> floats [4390912, 5439488)

// fp16 screen error bound: |d~ - dv_serial| <= 2*(Sum|z_i e_i| <= 0.295)*2^-11
// + MFMA fp32 accum ~2e-6 + serial-vs-real 4e-5 ~= 3.5e-4. THETA_F = 2e-3
// gives 2.9x margin on the 2*eps requirement (7e-4). Emission vs running min
// with the SAME threshold is a provable superset (runmin >= Mt always).
#define THETA_F 2e-3f
#define CAND_CAP 16
// fp32 summation-ORDER noise (same products, butterfly vs serial chain):
// <= 2*256*ulp(0.35)/2 ~= 1.6e-5. Gate at 2*EPSC = 4e-4 (25x margin).
#define EPSC 2e-4f

typedef __attribute__((ext_vector_type(8))) _Float16 f16x8;
typedef __attribute__((ext_vector_type(4))) float f32x4;

// ------- pre: zsq/esq, f16 casts zh/eh, zero hist/counters/loss -------
__global__ void pre_kernel(const float* __restrict__ z, const float* __restrict__ E,
                           float* __restrict__ zsq, float* __restrict__ esq,
                           int* __restrict__ hist, float* __restrict__ loss,
                           unsigned short* __restrict__ zh,
                           unsigned short* __restrict__ eh,
                           int* __restrict__ nm, int* __restrict__ novf) {
    const int b = blockIdx.x;
    const int wave = threadIdx.x >> 6;
    const int lane = threadIdx.x & 63;
    if (b < NTOK / 4) {
        int token = b * 4 + wave;
        float4 v = ((const float4*)(z + (size_t)token * DIM))[lane];
        ushort4 h;
        h.x = __half_as_ushort(__float2half(v.x));
        h.y = __half_as_ushort(__float2half(v.y));
        h.z = __half_as_ushort(__float2half(v.z));
        h.w = __half_as_ushort(__float2half(v.w));
        *(ushort4*)(zh + (size_t)token * DIM + lane * 4) = h;
        float s = v.x * v.x + v.y * v.y + v.z * v.z + v.w * v.w;
        #pragma unroll
        for (int off = 32; off > 0; off >>= 1) s += __shfl_down(s, off);
        if (lane == 0) zsq[token] = s;
        if (b == 0 && threadIdx.x == 4) loss[0] = 0.0f;
        if (b == 0 && threadIdx.x == 5) { *nm = 0; *novf = 0; }
    } else {
        int eb = b - NTOK / 4;                 // 0..255
        int k = eb * 4 + wave;
        float4 v = ((const float4*)(E + (size_t)k * DIM))[lane];
        ushort4 h;
        h.x = __half_as_ushort(__float2half(v.x));
        h.y = __half_as_ushort(__float2half(v.y));
        h.z = __half_as_ushort(__float2half(v.z));
        h.w = __half_as_ushort(__float2half(v.w));
        *(ushort4*)(eh + (size_t)k * DIM + lane * 4) = h;
        float s = v.x * v.x + v.y * v.y + v.z * v.z + v.w * v.w;
        #pragma unroll
        for (int off = 32; off > 0; off >>= 1) s += __shfl_down(s, off);
        if (lane == 0) esq[k] = s;
        if (threadIdx.x < 4) hist[eb * 4 + threadIdx.x] = 0;
    }
}

// ---------------- f16 MFMA distance screen (token-owner) ----------
// One block OWNS 64 tokens: loops all 8 code-chunks with a running min.
// A (64x256 zh tile) staged in LDS once; B (128x32 eh chunk) staged per kt.
// Emission: d <= runmin_after_chunk + THETA_F (superset of final survivor
// set since runmin >= Mt). f16 screen -> ~2-4 emissions/token, 76% of
// tokens resolve to a single survivor (handled with no exact recheck).
__global__ __launch_bounds__(256) void dist_mfma_kernel(
        const unsigned short* __restrict__ zh, const unsigned short* __restrict__ eh,
        const float* __restrict__ esq,
        float* __restrict__ Mg, int* __restrict__ ccount,
        unsigned long long* __restrict__ cand) {
    __shared__ unsigned short Als[64 * 264];   // row 528B (16B-mult)
    __shared__ unsigned short Bls[128 * 40];
    __shared__ float scr[64][4];
    __shared__ float runmin[64];
    __shared__ int lcnt[64];

    const int tid = threadIdx.x;
    const int wn = tid >> 6;                 // wave -> 32-col quarter
    const int lane = tid & 63;
    const int l15 = lane & 15, l4 = lane >> 4;
    const int tok0 = blockIdx.x * 64;

    // stage A once: 64 rows x 256 cols = 2048 f16x8 chunks, 8 per thread
    #pragma unroll
    for (int q = 0; q < 8; ++q) {
        int c = tid + 256 * q;               // 0..2047
        int row = c >> 5, ch = c & 31;
        *(f16x8*)(Als + row * 264 + ch * 8) =
            *(const f16x8*)(zh + (size_t)(tok0 + row) * 256 + ch * 8);
    }
    if (tid < 64) { runmin[tid] = 3.4e38f; lcnt[tid] = 0; }
    __syncthreads();

    const int brow0 = tid >> 2, bch = tid & 3;   // B staging coords

    for (int c0 = 0; c0 < KCODES; c0 += 128) {
        f32x4 acc[4][2];
        #pragma unroll
        for (int i = 0; i < 4; ++i)
            #pragma unroll
            for (int j = 0; j < 2; ++j)
                acc[i][j] = (f32x4){0.f, 0.f, 0.f, 0.f};

        for (int kt = 0; kt < 8; ++kt) {
            const int kk = kt * 32;
            f16x8 b0 = *(const f16x8*)(
                eh + (size_t)(c0 + brow0) * 256 + kk + bch * 8);
            f16x8 b1 = *(const f16x8*)(
                eh + (size_t)(c0 + brow0 + 64) * 256 + kk + bch * 8);
            __syncthreads();                 // prior Bls reads / emits done
            *(f16x8*)(Bls + brow0 * 40 + bch * 8) = b0;
            *(f16x8*)(Bls + (brow0 + 64) * 40 + bch * 8) = b1;
            __syncthreads();
            f16x8 av[4], bv[2];
            #pragma unroll
            for (int i = 0; i < 4; ++i)
                av[i] = *(const f16x8*)(Als + (i * 16 + l15) * 264 + kk + l4 * 8);
            #pragma unroll
            for (int j = 0; j < 2; ++j)
                bv[j] = *(const f16x8*)(Bls + (wn * 32 + j * 16 + l15) * 40 + l4 * 8);
            #pragma unroll
            for (int i = 0; i < 4; ++i)
                #pragma unroll
                for (int j = 0; j < 2; ++j)
                    acc[i][j] = __builtin_amdgcn_mfma_f32_16x16x32_f16(
                        av[i], bv[j], acc[i][j], 0, 0, 0);
        }

        float sq[2];
        #pragma unroll
        for (int j = 0; j < 2; ++j) sq[j] = esq[c0 + wn * 32 + j * 16 + l15];

        #pragma unroll
        for (int i = 0; i < 4; ++i) {
            #pragma unroll
            for (int r = 0; r < 4; ++r) {
                float v = fminf(sq[0] - 2.0f * acc[i][0][r],
                                sq[1] - 2.0f * acc[i][1][r]);
                #pragma unroll
                for (int m = 1; m < 16; m <<= 1)
                    v = fminf(v, __shfl_xor(v, m));
                if (l15 == 0) scr[i * 16 + l4 * 4 + r][wn] = v;
            }
        }
        __syncthreads();
        if (tid < 64) {
            float m = fminf(fminf(scr[tid][0], scr[tid][1]),
                            fminf(scr[tid][2], scr[tid][3]));
            runmin[tid] = fminf(runmin[tid], m);
        }
        __syncthreads();
        #pragma unroll
        for (int i = 0; i < 4; ++i) {
            #pragma unroll
            for (int r = 0; r < 4; ++r) {
                const int row = i * 16 + l4 * 4 + r;
                const float thr = runmin[row] + THETA_F;
                #pragma unroll
                for (int j = 0; j < 2; ++j) {
                    float d = sq[j] - 2.0f * acc[i][j][r];
                    if (d <= thr) {
                        int slot = atomicAdd(&lcnt[row], 1);
                        if (slot < CAND_CAP)
                            cand[(size_t)slot * NTOK + tok0 + row] =
                                (((unsigned long long)__float_as_uint(d)) << 32) |
                                (unsigned)(c0 + wn * 32 + j * 16 + l15);
                    }
                }
            }
        }
    }
    __syncthreads();    // all emits / lcnt atomics done
    if (tid < 64) {
        Mg[tok0 + tid] = runmin[tid];
        ccount[tok0 + tid] = lcnt[tid];
    }
}

// ------- recheck_a: per-TOKEN filter at Mt + THETA_F --------------------
// nsurv==1 -> PROVABLY the serial-order argmin (any other code's exact dv
// exceeds it by > THETA_F - 2*eps_f16 > 0) -> write idx directly (76%).
// 2..8 -> mlist. >8 or cand overflow -> ovf full exact scan (~never).
__global__ __launch_bounds__(256) void recheck_a_kernel(
        const float* __restrict__ Mg, const int* __restrict__ ccount,
        const unsigned long long* __restrict__ cand,
        unsigned int* __restrict__ idx,
        int* __restrict__ mlist, int* __restrict__ nm,
        int* __restrict__ ovf, int* __restrict__ novf) {
    const int token = blockIdx.x * 256 + threadIdx.x;
    const int cnt = ccount[token];
    const float thr = Mg[token] + THETA_F;

    if (cnt > CAND_CAP) {
        int s = atomicAdd(novf, 1);
        ovf[s] = token;
        return;
    }
    int nsurv = 0;
    int firstcode = 0;
    for (int s = 0; s < cnt; ++s) {
        unsigned long long e = cand[(size_t)s * NTOK + token];
        float dt = __uint_as_float((unsigned)(e >> 32));
        if (dt <= thr) {
            ++nsurv;
            if (nsurv == 1) firstcode = (int)(unsigned)(e & 0x3FFull);
        }
    }
    if (nsurv == 1) {
        idx[token] = (unsigned)firstcode;
    } else if (nsurv >= 2 && nsurv <= 8) {
        int m = atomicAdd(nm, 1);
        mlist[m] = token;
    } else {
        int s = atomicAdd(novf, 1);   // nsurv==0 impossible; >8 ultra-rare
        ovf[s] = token;
    }
}

// ------- recheck_b: wave per multi-survivor token (nsurv in [2,8]) -------
// Survivors gathered to lanes; <=8 BATCHED coalesced E-row dots (butterfly).
// Gate: parallel m2-m1 > 4e-4 >> 1.6e-5 order-noise -> parallel argmin ==
// serial argmin -> write. Else lane-0 bit-exact serial chain on the <=2
// codes within 4e-4 (z/E rows L1-hot from the wave's own loads),
// first-index tie-break = reference semantics.
#define RB_BLOCKS 1024
__global__ __launch_bounds__(256) void recheck_b_kernel(
        const float* __restrict__ z, const float* __restrict__ E,
        const float* __restrict__ zsq, const float* __restrict__ esq,
        const float* __restrict__ Mg, const int* __restrict__ ccount,
        const unsigned long long* __restrict__ cand,
        const int* __restrict__ mlist, const int* __restrict__ nm,
        const int* __restrict__ ovf, const int* __restrict__ novf,
        unsigned int* __restrict__ idx) {
    const int wave = threadIdx.x >> 6, lane = threadIdx.x & 63;
    const int gw = blockIdx.x * 4 + wave;
    const int n = *nm;
    for (int m = gw; m < n; m += RB_BLOCKS * 4) {
        const int token = mlist[m];
        const int cnt = ccount[token];         // <= 16
        const float thr = Mg[token] + THETA_F;
        const float An = zsq[token];
        const float4 zv = *(const float4*)(z + (size_t)token * DIM + lane * 4);
        unsigned long long e = 0x7F80000000000000ull;   // dt=+inf -> filtered
        if (lane < cnt) e = cand[(size_t)lane * NTOK + token];
        const float dt = __uint_as_float((unsigned)(e >> 32));
        const int ec = (int)(unsigned)(e & 0x3FFull);
        const unsigned long long bm0 = __ballot(lane < cnt && dt <= thr);
        unsigned long long bm = bm0;
        const int ns = __popcll(bm0);          // 2..8 (recheck_a guarantee)

        float m1 = 3.4e38f, m2 = 3.4e38f; int a1 = 0x7fffffff;
        int mycode = 0; float mydv = 3.4e38f;
        #pragma unroll
        for (int i = 0; i < 8; ++i) {
            if (i < ns) {
                const int s = __ffsll(bm) - 1; bm &= bm - 1;
                const int code = __shfl(ec, s);
                const float4 ev = *(const float4*)(E + (size_t)code * DIM + lane * 4);
                float p = fmaf(zv.x, ev.x, 0.0f);
                p = fmaf(zv.y, ev.y, p);
                p = fmaf(zv.z, ev.z, p);
                p = fmaf(zv.w, ev.w, p);
                #pragma unroll
                for (int o = 1; o < 64; o <<= 1) p += __shfl_xor(p, o);
                const float dv = (An + esq[code]) - 2.0f * p;
                if (dv < m1 || (dv == m1 && code < a1)) { m2 = m1; m1 = dv; a1 = code; }
                else if (dv < m2) m2 = dv;
                if (lane == i) { mycode = code; mydv = dv; }
            }
        }
        if (m2 - m1 > 2.0f * EPSC) {
            if (lane == 0) idx[token] = (unsigned)a1;
        } else {
            // ambiguous: bit-exact serial chains for codes within 2*EPSC of m1
            float b1 = 3.4e38f; int ai = 0x7fffffff;
            for (int s = 0; s < ns; ++s) {
                const int code = __shfl(mycode, s);
                const float dvp = __shfl(mydv, s);
                if (dvp <= m1 + 2.0f * EPSC && lane == 0) {
                    const float4* zp = (const float4*)(z + (size_t)token * DIM);
                    const float4* ep = (const float4*)(E + (size_t)code * DIM);
                    float acc = 0.0f;
                    #pragma unroll 8
                    for (int q = 0; q < 64; ++q) {
                        float4 a = zp[q], b = ep[q];
                        acc = fmaf(a.x, b.x, acc); acc = fmaf(a.y, b.y, acc);
                        acc = fmaf(a.z, b.z, acc); acc = fmaf(a.w, b.w, acc);
                    }
                    float dv = (An + esq[code]) - 2.0f * acc;
                    if (dv < b1 || (dv == b1 && code < ai)) { b1 = dv; ai = code; }
                }
            }
            if (lane == 0) idx[token] = (unsigned)ai;
        }
    }
    // overflow tokens (expected ~0): wave-per-token full exact serial scan
    const int nov = *novf;
    for (int w = gw; w < nov; w += RB_BLOCKS * 4) {
        const int token = ovf[w];
        const float An = zsq[token];
        const float4* zp = (const float4*)(z + (size_t)token * DIM);
        float best = 3.4e38f; int bid = 0x7fffffff;
        for (int code = lane; code < KCODES; code += 64) {
            const float4* ep = (const float4*)(E + (size_t)code * DIM);
            float acc = 0.0f;
            for (int q = 0; q < 64; ++q) {
                float4 a = zp[q], b = ep[q];
                acc = fmaf(a.x, b.x, acc); acc = fmaf(a.y, b.y, acc);
                acc = fmaf(a.z, b.z, acc); acc = fmaf(a.w, b.w, acc);
            }
            float dv = (An + esq[code]) - 2.0f * acc;
            if (dv < best || (dv == best && code < bid)) { best = dv; bid = code; }
        }
        #pragma unroll
        for (int mm = 1; mm < 64; mm <<= 1) {
            float ov = __shfl_xor(best, mm); int oi = __shfl_xor(bid, mm);
            if (ov < best || (ov == best && oi < bid)) { best = ov; bid = oi; }
        }
        if (lane == 0) idx[token] = (unsigned)bid;
    }
}

// ------- mid: hist, quant gather, loss, idx float-out -------
__global__ __launch_bounds__(256) void mid_kernel(
        const float* __restrict__ z, const float* __restrict__ E,
        const unsigned int* __restrict__ idxarr,
        float* __restrict__ idx_out, int* __restrict__ hist,
        float* __restrict__ quant, float* __restrict__ loss_acc) {
    __shared__ float ls[4];
    const int wave = threadIdx.x >> 6;
    const int lane = threadIdx.x & 63;
    const int token = blockIdx.x * 4 + wave;
    const int idx = (int)idxarr[token];

    if (lane == 0) {
        idx_out[token] = (float)idx;
        atomicAdd(&hist[idx], 1);
    }

    const float4 ev = *(const float4*)(E + (size_t)idx * DIM + lane * 4);
    const float4 zv = *(const float4*)(z + (size_t)token * DIM + lane * 4);
    *(float4*)(quant + (size_t)token * DIM + lane * 4) = ev;

    float dx = zv.x - ev.x, dy = zv.y - ev.y, dz = zv.z - ev.z, dww = zv.w - ev.w;
    float l = dx * dx + dy * dy + dz * dz + dww * dww;
    #pragma unroll
    for (int off = 32; off > 0; off >>= 1) l += __shfl_down(l, off);
    if (lane == 0) ls[wave] = l;
    __syncthreads();
    if (threadIdx.x == 0)
        atomicAdd(loss_acc, ls[0] + ls[1] + ls[2] + ls[3]);
}

// ------- cs: cluster-size normalize + hist prefix-sum (offs/cursor) -------
__global__ __launch_bounds__(256) void cs_kernel(
        const int* __restrict__ hist, const float* __restrict__ ema_cs,
        float* __restrict__ cs_out, int* __restrict__ offs,
        int* __restrict__ cursor) {
    __shared__ float f[256];
    __shared__ int hs[256];
    const int tid = threadIdx.x;
    float pre4[4]; int h4[4];
    float part = 0.0f; int hp = 0;
    #pragma unroll
    for (int q = 0; q < 4; ++q) {
        int k = tid * 4 + q;
        h4[q] = hist[k];
        pre4[q] = ema_cs[k] * DECAY + (1.0f - DECAY) * (float)h4[q];
        part += pre4[q];
        hp += h4[q];
    }
    f[tid] = part; hs[tid] = hp;
    __syncthreads();
    #pragma unroll
    for (int off = 1; off < 256; off <<= 1) {
        int v = (tid >= off) ? hs[tid - off] : 0;
        __syncthreads();
        hs[tid] += v;
        __syncthreads();
    }
    int run = hs[tid] - hp;                 // exclusive base for this thread
    #pragma unroll
    for (int q = 0; q < 4; ++q) {
        int k = tid * 4 + q;
        offs[k] = run; cursor[k] = run;
        run += h4[q];
    }
    if (tid == 255) offs[KCODES] = run;     // = NTOK
    for (int s = 128; s > 0; s >>= 1) {
        if (tid < s) f[tid] += f[tid + s];
        __syncthreads();
    }
    float n = f[0];
    #pragma unroll
    for (int q = 0; q < 4; ++q) {
        int k = tid * 4 + q;
        cs_out[k] = (pre4[q] + EPSILON) / (n + KCODES * EPSILON) * n;
    }
}

// ------- scatter: counting-sort tokens into per-code buckets -------
__global__ __launch_bounds__(256) void scatter_kernel(
        const unsigned int* __restrict__ idxarr,
        int* __restrict__ cursor, int* __restrict__ tlist) {
    const int t = blockIdx.x * 256 + threadIdx.x;
    const int idx = (int)idxarr[t];
    const int pos = atomicAdd(&cursor[idx], 1);
    tlist[pos] = t;
}

// ------- fin_gather: dw[k] = sum of z rows assigned to code k -------
__global__ __launch_bounds__(256) void fin_gather_kernel(
        const float* __restrict__ z, const int* __restrict__ offs,
        const int* __restrict__ tlist, float* __restrict__ dw) {
    __shared__ float4 red[4][64];
    const int k = blockIdx.x;
    const int grp = threadIdx.x >> 6;
    const int lane = threadIdx.x & 63;
    const int s = offs[k], e = offs[k + 1];
    float4 acc = {0.f, 0.f, 0.f, 0.f};
    for (int i = s + grp; i < e; i += 4) {
        const int t = tlist[i];
        const float4 v = *(const float4*)(z + (size_t)t * DIM + lane * 4);
        acc.x += v.x; acc.y += v.y; acc.z += v.z; acc.w += v.w;
    }
    red[grp][lane] = acc;
    __syncthreads();
    if (grp == 0) {
        float4 a = red[0][lane], b = red[1][lane];
        float4 c = red[2][lane], d = red[3][lane];
        float4 o;
        o.x = (a.x + b.x) + (c.x + d.x);
        o.y = (a.y + b.y) + (c.y + d.y);
        o.z = (a.z + b.z) + (c.z + d.z);
        o.w = (a.w + b.w) + (c.w + d.w);
        *(float4*)(dw + (size_t)k * DIM + lane * 4) = o;
    }
}

// ------- fin: new_ema_w & new_embedding (+ loss finalize) -------
__global__ __launch_bounds__(256) void fin_kernel(
        const float* __restrict__ ema_w, const float* __restrict__ cs,
        float* __restrict__ emaw_inout /* holds dw */, float* __restrict__ emb_out,
        float* __restrict__ loss_inout) {
    const int i = blockIdx.x * 256 + threadIdx.x;   // f4 index, 65536 total
    const int k = i >> 6;
    float4 d = ((const float4*)emaw_inout)[i];
    float4 w = ((const float4*)ema_w)[i];
    float4 nw;
    nw.x = w.x * DECAY + (1.0f - DECAY) * d.x;
    nw.y = w.y * DECAY + (1.0f - DECAY) * d.y;
    nw.z = w.z * DECAY + (1.0f - DECAY) * d.z;
    nw.w = w.w * DECAY + (1.0f - DECAY) * d.w;
    ((float4*)emaw_inout)[i] = nw;
    float inv = 1.0f / cs[k];
    float4 e; e.x = nw.x * inv; e.y = nw.y * inv; e.z = nw.z * inv; e.w = nw.w * inv;
    ((float4*)emb_out)[i] = e;
    if (i == 0)
        loss_inout[0] = COMMITMENT_COST * loss_inout[0] / (float)((size_t)NTOK * DIM);
}

extern "C" void kernel_launch(void* const* d_in, const int* in_sizes, int n_in,
                              void* d_out, int out_size, void* d_ws, size_t ws_size,
                              hipStream_t stream) {
    const float* z      = (const float*)d_in[0];
    const float* E      = (const float*)d_in[1];
    const float* ema_cs = (const float*)d_in[2];
    const float* ema_w  = (const float*)d_in[3];
    float* out = (float*)d_out;

    float* emb = out + O_EMB;
    unsigned int* idx = (unsigned int*)(emb + SE_IDX);
    float* esq  = emb + SE_ESQ;
    float* zsq  = emb + SE_ZSQ;
    int*   hist = (int*)(emb + SE_HIST);
    int*   nm     = (int*)(emb + SE_NM);
    int*   novf   = (int*)(emb + SE_NOVF);
    int*   mlist  = (int*)(emb + SE_MLIST);
    int*   ovf    = (int*)(emb + SE_OVF);
    int*   offs   = (int*)(emb + SE_OFFS);
    int*   cursor = (int*)(emb + SE_CUR);
    int*   tlist  = (int*)(emb + SE_TLIST);

    unsigned short* zh = (unsigned short*)(out + SQ_ZH);
    unsigned short* eh = (unsigned short*)(out + SQ_EH);
    float* Mg = out + SQ_MG;
    int* ccount = (int*)(out + SQ_CC);
    unsigned long long* cand = (unsigned long long*)(out + SQ_CAND);

    pre_kernel<<<NTOK / 4 + KCODES / 4, 256, 0, stream>>>(
        z, E, zsq, esq, hist, out + O_LOSS, zh, eh, nm, novf);
    dist_mfma_kernel<<<NTOK / 64, 256, 0, stream>>>(
        zh, eh, esq, Mg, ccount, cand);
    recheck_a_kernel<<<NTOK / 256, 256, 0, stream>>>(
        Mg, ccount, cand, idx, mlist, nm, ovf, novf);
    recheck_b_kernel<<<RB_BLOCKS, 256, 0, stream>>>(
        z, E, zsq, esq, Mg, ccount, cand, mlist, nm, ovf, novf, idx);
    mid_kernel<<<NTOK / 4, 256, 0, stream>>>(z, E, idx, out + O_IDX, hist,
                                             out + O_QUANT, out + O_LOSS);
    cs_kernel<<<1, 256, 0, stream>>>(hist, ema_cs, out + O_CS, offs, cursor);
    scatter_kernel<<<NTOK / 256, 256, 0, stream>>>(idx, cursor, tlist);
    fin_gather_kernel<<<KCODES, 256, 0, stream>>>(z, offs, tlist, out + O_EMAW);
    fin_kernel<<<256, 256, 0, stream>>>(ema_w, out + O_CS, out + O_EMAW, emb,
                                        out + O_LOSS);
}

// Round 11
// 239.550 us; speedup vs baseline: 2.2734x; 1.4013x over previous
//
#include <hip/hip_runtime.h>
#include <hip/hip_fp16.h>
#include <math.h>

#define COMMITMENT_COST 0.25f
#define DECAY 0.99f
#define EPSILON 1e-05f
#define KCODES 1024
#define DIM 256
#define NTOK 32768

// out-buffer float offsets (concatenated return tuple)
#define O_QUANT 0
#define O_LOSS  8388608
#define O_IDX   8388609
#define O_CS    8421377
#define O_EMAW  8422401
#define O_EMB   8684545

// scratch in the new_embedding slot (262144 floats, written LAST by fin).
#define SE_IDX    0        // u32[32768]: final code per token
#define SE_ESQ    32768    // f32[1024]
#define SE_ZSQ    33792    // f32[32768]
#define SE_HIST   66560    // int[1024]
#define SE_NM     67584    // int
#define SE_NOVF   67585    // int
#define SE_MLIST  67586    // int[32768]
#define SE_OVF    100354   // int[32768]
#define SE_OFFS   133122   // int[1025]
#define SE_CUR    134147   // int[1024]
#define SE_TLIST  135171   // int[32768] -> ends 167939
#define SE_LPART  167939   // f32[8192] -> ends 176131 < 262144

// scratch in the O_QUANT slot (8388608 floats, written by mid AFTER recheck).
#define SQ_ZH    0         // f16[32768*256] -> floats [0, 4194304)
#define SQ_EH    4194304   // f16[1024*256]  -> floats [4194304, 4325376)
#define SQ_MG    4325376   // f32[32768]
#define SQ_CC    4358144   // int[32768]
#define SQ_CAND  4390912   // u64[16][32768] TRANSPOSED -> floats [4390912, 5439488)

// fp16 screen error bound: |d~ - dv_serial| <= 2*(Sum|z_i e_i| <= 0.295)*2^-11
// + MFMA fp32 accum ~2e-6 + serial-vs-real 4e-5 ~= 3.5e-4. THETA_F = 2e-3
// gives 2.9x margin on the 2*eps requirement (7e-4). Emission vs running min
// with the SAME threshold is a provable superset (runmin >= Mt always).
#define THETA_F 2e-3f
#define CAND_CAP 16
// fp32 summation-ORDER noise (same products, butterfly vs serial chain):
// <= 2*256*ulp(0.35)/2 ~= 1.6e-5. Gate at 2*EPSC = 4e-4 (25x margin).
#define EPSC 2e-4f

typedef __attribute__((ext_vector_type(8))) _Float16 f16x8;
typedef __attribute__((ext_vector_type(4))) float f32x4;

// ------- pre: zsq/esq, f16 casts zh/eh, zero hist/counters/loss -------
__global__ void pre_kernel(const float* __restrict__ z, const float* __restrict__ E,
                           float* __restrict__ zsq, float* __restrict__ esq,
                           int* __restrict__ hist, float* __restrict__ loss,
                           unsigned short* __restrict__ zh,
                           unsigned short* __restrict__ eh,
                           int* __restrict__ nm, int* __restrict__ novf) {
    const int b = blockIdx.x;
    const int wave = threadIdx.x >> 6;
    const int lane = threadIdx.x & 63;
    if (b < NTOK / 4) {
        int token = b * 4 + wave;
        float4 v = ((const float4*)(z + (size_t)token * DIM))[lane];
        ushort4 h;
        h.x = __half_as_ushort(__float2half(v.x));
        h.y = __half_as_ushort(__float2half(v.y));
        h.z = __half_as_ushort(__float2half(v.z));
        h.w = __half_as_ushort(__float2half(v.w));
        *(ushort4*)(zh + (size_t)token * DIM + lane * 4) = h;
        float s = v.x * v.x + v.y * v.y + v.z * v.z + v.w * v.w;
        #pragma unroll
        for (int off = 32; off > 0; off >>= 1) s += __shfl_down(s, off);
        if (lane == 0) zsq[token] = s;
        if (b == 0 && threadIdx.x == 4) loss[0] = 0.0f;
        if (b == 0 && threadIdx.x == 5) { *nm = 0; *novf = 0; }
    } else {
        int eb = b - NTOK / 4;                 // 0..255
        int k = eb * 4 + wave;
        float4 v = ((const float4*)(E + (size_t)k * DIM))[lane];
        ushort4 h;
        h.x = __half_as_ushort(__float2half(v.x));
        h.y = __half_as_ushort(__float2half(v.y));
        h.z = __half_as_ushort(__float2half(v.z));
        h.w = __half_as_ushort(__float2half(v.w));
        *(ushort4*)(eh + (size_t)k * DIM + lane * 4) = h;
        float s = v.x * v.x + v.y * v.y + v.z * v.z + v.w * v.w;
        #pragma unroll
        for (int off = 32; off > 0; off >>= 1) s += __shfl_down(s, off);
        if (lane == 0) esq[k] = s;
        if (threadIdx.x < 4) hist[eb * 4 + threadIdx.x] = 0;
    }
}

// ---------------- f16 MFMA distance screen (token-owner) ----------
// One block OWNS 64 tokens: loops all 8 code-chunks with a running min.
// A (64x256 zh tile) staged in LDS once; B (128x32 eh chunk) staged per kt.
// Emission: d <= runmin_after_chunk + THETA_F (superset of final survivors).
__global__ __launch_bounds__(256) void dist_mfma_kernel(
        const unsigned short* __restrict__ zh, const unsigned short* __restrict__ eh,
        const float* __restrict__ esq,
        float* __restrict__ Mg, int* __restrict__ ccount,
        unsigned long long* __restrict__ cand) {
    __shared__ unsigned short Als[64 * 264];   // row 528B (16B-mult)
    __shared__ unsigned short Bls[128 * 40];
    __shared__ float scr[64][4];
    __shared__ float runmin[64];
    __shared__ int lcnt[64];

    const int tid = threadIdx.x;
    const int wn = tid >> 6;                 // wave -> 32-col quarter
    const int lane = tid & 63;
    const int l15 = lane & 15, l4 = lane >> 4;
    const int tok0 = blockIdx.x * 64;

    // stage A once: 64 rows x 256 cols = 2048 f16x8 chunks, 8 per thread
    #pragma unroll
    for (int q = 0; q < 8; ++q) {
        int c = tid + 256 * q;               // 0..2047
        int row = c >> 5, ch = c & 31;
        *(f16x8*)(Als + row * 264 + ch * 8) =
            *(const f16x8*)(zh + (size_t)(tok0 + row) * 256 + ch * 8);
    }
    if (tid < 64) { runmin[tid] = 3.4e38f; lcnt[tid] = 0; }
    __syncthreads();

    const int brow0 = tid >> 2, bch = tid & 3;   // B staging coords

    for (int c0 = 0; c0 < KCODES; c0 += 128) {
        f32x4 acc[4][2];
        #pragma unroll
        for (int i = 0; i < 4; ++i)
            #pragma unroll
            for (int j = 0; j < 2; ++j)
                acc[i][j] = (f32x4){0.f, 0.f, 0.f, 0.f};

        for (int kt = 0; kt < 8; ++kt) {
            const int kk = kt * 32;
            f16x8 b0 = *(const f16x8*)(
                eh + (size_t)(c0 + brow0) * 256 + kk + bch * 8);
            f16x8 b1 = *(const f16x8*)(
                eh + (size_t)(c0 + brow0 + 64) * 256 + kk + bch * 8);
            __syncthreads();                 // prior Bls reads / emits done
            *(f16x8*)(Bls + brow0 * 40 + bch * 8) = b0;
            *(f16x8*)(Bls + (brow0 + 64) * 40 + bch * 8) = b1;
            __syncthreads();
            f16x8 av[4], bv[2];
            #pragma unroll
            for (int i = 0; i < 4; ++i)
                av[i] = *(const f16x8*)(Als + (i * 16 + l15) * 264 + kk + l4 * 8);
            #pragma unroll
            for (int j = 0; j < 2; ++j)
                bv[j] = *(const f16x8*)(Bls + (wn * 32 + j * 16 + l15) * 40 + l4 * 8);
            #pragma unroll
            for (int i = 0; i < 4; ++i)
                #pragma unroll
                for (int j = 0; j < 2; ++j)
                    acc[i][j] = __builtin_amdgcn_mfma_f32_16x16x32_f16(
                        av[i], bv[j], acc[i][j], 0, 0, 0);
        }

        float sq[2];
        #pragma unroll
        for (int j = 0; j < 2; ++j) sq[j] = esq[c0 + wn * 32 + j * 16 + l15];

        #pragma unroll
        for (int i = 0; i < 4; ++i) {
            #pragma unroll
            for (int r = 0; r < 4; ++r) {
                float v = fminf(sq[0] - 2.0f * acc[i][0][r],
                                sq[1] - 2.0f * acc[i][1][r]);
                #pragma unroll
                for (int m = 1; m < 16; m <<= 1)
                    v = fminf(v, __shfl_xor(v, m));
                if (l15 == 0) scr[i * 16 + l4 * 4 + r][wn] = v;
            }
        }
        __syncthreads();
        if (tid < 64) {
            float m = fminf(fminf(scr[tid][0], scr[tid][1]),
                            fminf(scr[tid][2], scr[tid][3]));
            runmin[tid] = fminf(runmin[tid], m);
        }
        __syncthreads();
        #pragma unroll
        for (int i = 0; i < 4; ++i) {
            #pragma unroll
            for (int r = 0; r < 4; ++r) {
                const int row = i * 16 + l4 * 4 + r;
                const float thr = runmin[row] + THETA_F;
                #pragma unroll
                for (int j = 0; j < 2; ++j) {
                    float d = sq[j] - 2.0f * acc[i][j][r];
                    if (d <= thr) {
                        int slot = atomicAdd(&lcnt[row], 1);
                        if (slot < CAND_CAP)
                            cand[(size_t)slot * NTOK + tok0 + row] =
                                (((unsigned long long)__float_as_uint(d)) << 32) |
                                (unsigned)(c0 + wn * 32 + j * 16 + l15);
                    }
                }
            }
        }
    }
    __syncthreads();    // all emits / lcnt atomics done
    if (tid < 64) {
        Mg[tok0 + tid] = runmin[tid];
        ccount[tok0 + tid] = lcnt[tid];
    }
}

// ------- recheck_a: per-TOKEN filter at Mt + THETA_F --------------------
// nsurv==1 -> PROVABLY the serial-order argmin -> write idx directly (~76%).
// 2..8 -> mlist; overflow/weird -> ovf. Block-aggregated reservation: ONE
// atomicAdd(nm) + ONE atomicAdd(novf) per block (r9 fix: ~8K same-address
// atomics serialized at ~13ns = hidden 50-100us; now 128+128 total).
__global__ __launch_bounds__(256) void recheck_a_kernel(
        const float* __restrict__ Mg, const int* __restrict__ ccount,
        const unsigned long long* __restrict__ cand,
        unsigned int* __restrict__ idx,
        int* __restrict__ mlist, int* __restrict__ nm,
        int* __restrict__ ovf, int* __restrict__ novf) {
    __shared__ int ps[256];
    __shared__ int base_m, base_o;
    const int tid = threadIdx.x;
    const int token = blockIdx.x * 256 + tid;
    const int cnt = ccount[token];
    const float thr = Mg[token] + THETA_F;

    const bool isovf_cap = (cnt > CAND_CAP);
    int nsurv = 0;
    int firstcode = 0;
    if (!isovf_cap) {
        for (int s = 0; s < cnt; ++s) {
            unsigned long long e = cand[(size_t)s * NTOK + token];
            float dt = __uint_as_float((unsigned)(e >> 32));
            if (dt <= thr) {
                ++nsurv;
                if (nsurv == 1) firstcode = (int)(unsigned)(e & 0x3FFull);
            }
        }
    }
    const bool ismulti = !isovf_cap && nsurv >= 2 && nsurv <= 8;
    const bool isovf = isovf_cap || (!isovf_cap && (nsurv == 0 || nsurv > 8));
    const int want = (ismulti ? 1 : 0) | ((isovf ? 1 : 0) << 16);

    ps[tid] = want;
    __syncthreads();
    #pragma unroll
    for (int off = 1; off < 256; off <<= 1) {
        int v = (tid >= off) ? ps[tid - off] : 0;
        __syncthreads();
        ps[tid] += v;
        __syncthreads();
    }
    if (tid == 255) {
        int tot = ps[255];
        base_m = (tot & 0xFFFF) ? atomicAdd(nm, tot & 0xFFFF) : 0;
        base_o = (tot >> 16) ? atomicAdd(novf, tot >> 16) : 0;
    }
    __syncthreads();
    const int off_m = (ps[tid] - want) & 0xFFFF;
    const int off_o = (ps[tid] - want) >> 16;

    if (!isovf_cap && nsurv == 1) idx[token] = (unsigned)firstcode;
    if (ismulti) mlist[base_m + off_m] = token;
    if (isovf)   ovf[base_o + off_o] = token;
}

// ------- recheck_b: wave per multi-survivor token (nsurv in [2,8]) -------
// Survivors gathered to lanes; <=8 BATCHED coalesced E-row dots (butterfly).
// Gate: parallel m2-m1 > 4e-4 >> 1.6e-5 order-noise -> parallel argmin ==
// serial argmin -> write. Else lane-0 bit-exact serial chain on the codes
// within 4e-4, first-index tie-break = reference semantics.
#define RB_BLOCKS 1024
__global__ __launch_bounds__(256) void recheck_b_kernel(
        const float* __restrict__ z, const float* __restrict__ E,
        const float* __restrict__ zsq, const float* __restrict__ esq,
        const float* __restrict__ Mg, const int* __restrict__ ccount,
        const unsigned long long* __restrict__ cand,
        const int* __restrict__ mlist, const int* __restrict__ nm,
        const int* __restrict__ ovf, const int* __restrict__ novf,
        unsigned int* __restrict__ idx) {
    const int wave = threadIdx.x >> 6, lane = threadIdx.x & 63;
    const int gw = blockIdx.x * 4 + wave;
    const int n = *nm;
    for (int m = gw; m < n; m += RB_BLOCKS * 4) {
        const int token = mlist[m];
        const int cnt = ccount[token];         // <= 16
        const float thr = Mg[token] + THETA_F;
        const float An = zsq[token];
        const float4 zv = *(const float4*)(z + (size_t)token * DIM + lane * 4);
        unsigned long long e = 0x7F80000000000000ull;   // dt=+inf -> filtered
        if (lane < cnt) e = cand[(size_t)lane * NTOK + token];
        const float dt = __uint_as_float((unsigned)(e >> 32));
        const int ec = (int)(unsigned)(e & 0x3FFull);
        const unsigned long long bm0 = __ballot(lane < cnt && dt <= thr);
        unsigned long long bm = bm0;
        const int ns = __popcll(bm0);          // 2..8 (recheck_a guarantee)

        float m1 = 3.4e38f, m2 = 3.4e38f; int a1 = 0x7fffffff;
        int mycode = 0; float mydv = 3.4e38f;
        #pragma unroll
        for (int i = 0; i < 8; ++i) {
            if (i < ns) {
                const int s = __ffsll(bm) - 1; bm &= bm - 1;
                const int code = __shfl(ec, s);
                const float4 ev = *(const float4*)(E + (size_t)code * DIM + lane * 4);
                float p = fmaf(zv.x, ev.x, 0.0f);
                p = fmaf(zv.y, ev.y, p);
                p = fmaf(zv.z, ev.z, p);
                p = fmaf(zv.w, ev.w, p);
                #pragma unroll
                for (int o = 1; o < 64; o <<= 1) p += __shfl_xor(p, o);
                const float dv = (An + esq[code]) - 2.0f * p;
                if (dv < m1 || (dv == m1 && code < a1)) { m2 = m1; m1 = dv; a1 = code; }
                else if (dv < m2) m2 = dv;
                if (lane == i) { mycode = code; mydv = dv; }
            }
        }
        if (m2 - m1 > 2.0f * EPSC) {
            if (lane == 0) idx[token] = (unsigned)a1;
        } else {
            // ambiguous: bit-exact serial chains for codes within 2*EPSC of m1
            float b1 = 3.4e38f; int ai = 0x7fffffff;
            for (int s = 0; s < ns; ++s) {
                const int code = __shfl(mycode, s);
                const float dvp = __shfl(mydv, s);
                if (dvp <= m1 + 2.0f * EPSC && lane == 0) {
                    const float4* zp = (const float4*)(z + (size_t)token * DIM);
                    const float4* ep = (const float4*)(E + (size_t)code * DIM);
                    float acc = 0.0f;
                    #pragma unroll 8
                    for (int q = 0; q < 64; ++q) {
                        float4 a = zp[q], b = ep[q];
                        acc = fmaf(a.x, b.x, acc); acc = fmaf(a.y, b.y, acc);
                        acc = fmaf(a.z, b.z, acc); acc = fmaf(a.w, b.w, acc);
                    }
                    float dv = (An + esq[code]) - 2.0f * acc;
                    if (dv < b1 || (dv == b1 && code < ai)) { b1 = dv; ai = code; }
                }
            }
            if (lane == 0) idx[token] = (unsigned)ai;
        }
    }
    // overflow tokens (expected ~0): wave-per-token full exact serial scan
    const int nov = *novf;
    for (int w = gw; w < nov; w += RB_BLOCKS * 4) {
        const int token = ovf[w];
        const float An = zsq[token];
        const float4* zp = (const float4*)(z + (size_t)token * DIM);
        float best = 3.4e38f; int bid = 0x7fffffff;
        for (int code = lane; code < KCODES; code += 64) {
            const float4* ep = (const float4*)(E + (size_t)code * DIM);
            float acc = 0.0f;
            for (int q = 0; q < 64; ++q) {
                float4 a = zp[q], b = ep[q];
                acc = fmaf(a.x, b.x, acc); acc = fmaf(a.y, b.y, acc);
                acc = fmaf(a.z, b.z, acc); acc = fmaf(a.w, b.w, acc);
            }
            float dv = (An + esq[code]) - 2.0f * acc;
            if (dv < best || (dv == best && code < bid)) { best = dv; bid = code; }
        }
        #pragma unroll
        for (int mm = 1; mm < 64; mm <<= 1) {
            float ov = __shfl_xor(best, mm); int oi = __shfl_xor(bid, mm);
            if (ov < best || (ov == best && oi < bid)) { best = ov; bid = oi; }
        }
        if (lane == 0) idx[token] = (unsigned)bid;
    }
}

// ------- mid: hist, quant gather, loss PARTIAL (no same-address atomic) ----
__global__ __launch_bounds__(256) void mid_kernel(
        const float* __restrict__ z, const float* __restrict__ E,
        const unsigned int* __restrict__ idxarr,
        float* __restrict__ idx_out, int* __restrict__ hist,
        float* __restrict__ quant, float* __restrict__ lpart) {
    __shared__ float ls[4];
    const int wave = threadIdx.x >> 6;
    const int lane = threadIdx.x & 63;
    const int token = blockIdx.x * 4 + wave;
    const int idx = (int)idxarr[token];

    if (lane == 0) {
        idx_out[token] = (float)idx;
        atomicAdd(&hist[idx], 1);
    }

    const float4 ev = *(const float4*)(E + (size_t)idx * DIM + lane * 4);
    const float4 zv = *(const float4*)(z + (size_t)token * DIM + lane * 4);
    *(float4*)(quant + (size_t)token * DIM + lane * 4) = ev;

    float dx = zv.x - ev.x, dy = zv.y - ev.y, dz = zv.z - ev.z, dww = zv.w - ev.w;
    float l = dx * dx + dy * dy + dz * dz + dww * dww;
    #pragma unroll
    for (int off = 32; off > 0; off >>= 1) l += __shfl_down(l, off);
    if (lane == 0) ls[wave] = l;
    __syncthreads();
    if (threadIdx.x == 0)
        lpart[blockIdx.x] = (ls[0] + ls[1]) + (ls[2] + ls[3]);
}

// ------- cs: cluster-size normalize + hist prefix-sum + loss reduce -------
__global__ __launch_bounds__(256) void cs_kernel(
        const int* __restrict__ hist, const float* __restrict__ ema_cs,
        float* __restrict__ cs_out, int* __restrict__ offs,
        int* __restrict__ cursor, const float* __restrict__ lpart,
        float* __restrict__ loss) {
    __shared__ float f[256];
    __shared__ int hs[256];
    const int tid = threadIdx.x;
    float pre4[4]; int h4[4];
    float part = 0.0f; int hp = 0;
    #pragma unroll
    for (int q = 0; q < 4; ++q) {
        int k = tid * 4 + q;
        h4[q] = hist[k];
        pre4[q] = ema_cs[k] * DECAY + (1.0f - DECAY) * (float)h4[q];
        part += pre4[q];
        hp += h4[q];
    }
    f[tid] = part; hs[tid] = hp;
    __syncthreads();
    #pragma unroll
    for (int off = 1; off < 256; off <<= 1) {
        int v = (tid >= off) ? hs[tid - off] : 0;
        __syncthreads();
        hs[tid] += v;
        __syncthreads();
    }
    int run = hs[tid] - hp;                 // exclusive base for this thread
    #pragma unroll
    for (int q = 0; q < 4; ++q) {
        int k = tid * 4 + q;
        offs[k] = run; cursor[k] = run;
        run += h4[q];
    }
    if (tid == 255) offs[KCODES] = run;     // = NTOK
    for (int s = 128; s > 0; s >>= 1) {
        if (tid < s) f[tid] += f[tid + s];
        __syncthreads();
    }
    float n = f[0];
    #pragma unroll
    for (int q = 0; q < 4; ++q) {
        int k = tid * 4 + q;
        cs_out[k] = (pre4[q] + EPSILON) / (n + KCODES * EPSILON) * n;
    }
    // ---- loss: reduce the 8192 per-block partials (coalesced) ----
    float lp = 0.0f;
    #pragma unroll
    for (int q = 0; q < 32; ++q) lp += lpart[tid + 256 * q];
    __syncthreads();
    f[tid] = lp;
    __syncthreads();
    for (int s = 128; s > 0; s >>= 1) {
        if (tid < s) f[tid] += f[tid + s];
        __syncthreads();
    }
    if (tid == 0) loss[0] = f[0];
}

// ------- scatter: counting-sort tokens into per-code buckets -------
__global__ __launch_bounds__(256) void scatter_kernel(
        const unsigned int* __restrict__ idxarr,
        int* __restrict__ cursor, int* __restrict__ tlist) {
    const int t = blockIdx.x * 256 + threadIdx.x;
    const int idx = (int)idxarr[t];
    const int pos = atomicAdd(&cursor[idx], 1);
    tlist[pos] = t;
}

// ------- fin_gather: dw[k] = sum of z rows assigned to code k -------
__global__ __launch_bounds__(256) void fin_gather_kernel(
        const float* __restrict__ z, const int* __restrict__ offs,
        const int* __restrict__ tlist, float* __restrict__ dw) {
    __shared__ float4 red[4][64];
    const int k = blockIdx.x;
    const int grp = threadIdx.x >> 6;
    const int lane = threadIdx.x & 63;
    const int s = offs[k], e = offs[k + 1];
    float4 acc = {0.f, 0.f, 0.f, 0.f};
    for (int i = s + grp; i < e; i += 4) {
        const int t = tlist[i];
        const float4 v = *(const float4*)(z + (size_t)t * DIM + lane * 4);
        acc.x += v.x; acc.y += v.y; acc.z += v.z; acc.w += v.w;
    }
    red[grp][lane] = acc;
    __syncthreads();
    if (grp == 0) {
        float4 a = red[0][lane], b = red[1][lane];
        float4 c = red[2][lane], d = red[3][lane];
        float4 o;
        o.x = (a.x + b.x) + (c.x + d.x);
        o.y = (a.y + b.y) + (c.y + d.y);
        o.z = (a.z + b.z) + (c.z + d.z);
        o.w = (a.w + b.w) + (c.w + d.w);
        *(float4*)(dw + (size_t)k * DIM + lane * 4) = o;
    }
}

// ------- fin: new_ema_w & new_embedding (+ loss finalize) -------
__global__ __launch_bounds__(256) void fin_kernel(
        const float* __restrict__ ema_w, const float* __restrict__ cs,
        float* __restrict__ emaw_inout /* holds dw */, float* __restrict__ emb_out,
        float* __restrict__ loss_inout) {
    const int i = blockIdx.x * 256 + threadIdx.x;   // f4 index, 65536 total
    const int k = i >> 6;
    float4 d = ((const float4*)emaw_inout)[i];
    float4 w = ((const float4*)ema_w)[i];
    float4 nw;
    nw.x = w.x * DECAY + (1.0f - DECAY) * d.x;
    nw.y = w.y * DECAY + (1.0f - DECAY) * d.y;
    nw.z = w.z * DECAY + (1.0f - DECAY) * d.z;
    nw.w = w.w * DECAY + (1.0f - DECAY) * d.w;
    ((float4*)emaw_inout)[i] = nw;
    float inv = 1.0f / cs[k];
    float4 e; e.x = nw.x * inv; e.y = nw.y * inv; e.z = nw.z * inv; e.w = nw.w * inv;
    ((float4*)emb_out)[i] = e;
    if (i == 0)
        loss_inout[0] = COMMITMENT_COST * loss_inout[0] / (float)((size_t)NTOK * DIM);
}

extern "C" void kernel_launch(void* const* d_in, const int* in_sizes, int n_in,
                              void* d_out, int out_size, void* d_ws, size_t ws_size,
                              hipStream_t stream) {
    const float* z      = (const float*)d_in[0];
    const float* E      = (const float*)d_in[1];
    const float* ema_cs = (const float*)d_in[2];
    const float* ema_w  = (const float*)d_in[3];
    float* out = (float*)d_out;

    float* emb = out + O_EMB;
    unsigned int* idx = (unsigned int*)(emb + SE_IDX);
    float* esq  = emb + SE_ESQ;
    float* zsq  = emb + SE_ZSQ;
    int*   hist = (int*)(emb + SE_HIST);
    int*   nm     = (int*)(emb + SE_NM);
    int*   novf   = (int*)(emb + SE_NOVF);
    int*   mlist  = (int*)(emb + SE_MLIST);
    int*   ovf    = (int*)(emb + SE_OVF);
    int*   offs   = (int*)(emb + SE_OFFS);
    int*   cursor = (int*)(emb + SE_CUR);
    int*   tlist  = (int*)(emb + SE_TLIST);
    float* lpart  = emb + SE_LPART;

    unsigned short* zh = (unsigned short*)(out + SQ_ZH);
    unsigned short* eh = (unsigned short*)(out + SQ_EH);
    float* Mg = out + SQ_MG;
    int* ccount = (int*)(out + SQ_CC);
    unsigned long long* cand = (unsigned long long*)(out + SQ_CAND);

    pre_kernel<<<NTOK / 4 + KCODES / 4, 256, 0, stream>>>(
        z, E, zsq, esq, hist, out + O_LOSS, zh, eh, nm, novf);
    dist_mfma_kernel<<<NTOK / 64, 256, 0, stream>>>(
        zh, eh, esq, Mg, ccount, cand);
    recheck_a_kernel<<<NTOK / 256, 256, 0, stream>>>(
        Mg, ccount, cand, idx, mlist, nm, ovf, novf);
    recheck_b_kernel<<<RB_BLOCKS, 256, 0, stream>>>(
        z, E, zsq, esq, Mg, ccount, cand, mlist, nm, ovf, novf, idx);
    mid_kernel<<<NTOK / 4, 256, 0, stream>>>(z, E, idx, out + O_IDX, hist,
                                             out + O_QUANT, lpart);
    cs_kernel<<<1, 256, 0, stream>>>(hist, ema_cs, out + O_CS, offs, cursor,
                                     lpart, out + O_LOSS);
    scatter_kernel<<<NTOK / 256, 256, 0, stream>>>(idx, cursor, tlist);
    fin_gather_kernel<<<KCODES, 256, 0, stream>>>(z, offs, tlist, out + O_EMAW);
    fin_kernel<<<256, 256, 0, stream>>>(ema_w, out + O_CS, out + O_EMAW, emb,
                                        out + O_LOSS);
}

// Round 12
// 223.562 us; speedup vs baseline: 2.4360x; 1.0715x over previous
//
#include <hip/hip_runtime.h>
#include <hip/hip_fp16.h>
#include <math.h>

#define COMMITMENT_COST 0.25f
#define DECAY 0.99f
#define EPSILON 1e-05f
#define KCODES 1024
#define DIM 256
#define NTOK 32768

// out-buffer float offsets (concatenated return tuple)
#define O_QUANT 0
#define O_LOSS  8388608
#define O_IDX   8388609
#define O_CS    8421377
#define O_EMAW  8422401
#define O_EMB   8684545

// scratch in the new_embedding slot (262144 floats, written LAST by fin).
#define SE_IDX    0        // u32[32768]: final code per token
#define SE_ESQ    32768    // f32[1024]
#define SE_ZSQ    33792    // f32[32768]
#define SE_HIST   66560    // int[1024]
#define SE_NM     67584    // int
#define SE_NOVF   67585    // int
#define SE_MLIST  67586    // int[32768]
#define SE_OVF    100354   // int[32768]
#define SE_OFFS   133122   // int[1025]
#define SE_CUR    134147   // int[1024]
#define SE_TLIST  135171   // int[32768] -> ends 167939
#define SE_LPART  167939   // f32[8192] -> ends 176131 < 262144

// scratch in the O_QUANT slot (8388608 floats, written by mid AFTER recheck).
#define SQ_ZH    0         // f16[32768*256] -> floats [0, 4194304)
#define SQ_EH    4194304   // f16[1024*256]  -> floats [4194304, 4325376)
#define SQ_MG    4325376   // f32[32768]
#define SQ_CC    4358144   // int[32768]
#define SQ_CAND  4390912   // u64[16][32768] TRANSPOSED -> floats [4390912, 5439488)

// fp16 screen error bound: |d~ - dv_serial| <= 2*(Sum|z_i e_i| <= 0.295)*2^-11
// + MFMA fp32 accum ~2e-6 + serial-vs-real 4e-5 ~= 3.5e-4. THETA_F = 2e-3
// gives 2.9x margin on the 2*eps requirement (7e-4). Emission vs running min
// with the SAME threshold is a provable superset (runmin >= Mt always).
#define THETA_F 2e-3f
#define CAND_CAP 16
// fp32 summation-ORDER noise (same products, butterfly vs serial chain):
// <= 2*256*ulp(0.35)/2 ~= 1.6e-5. Gate at 2*EPSC = 4e-4 (25x margin).
#define EPSC 2e-4f

typedef __attribute__((ext_vector_type(8))) _Float16 f16x8;
typedef __attribute__((ext_vector_type(4))) float f32x4;

// ------- pre: zsq/esq, f16 casts zh/eh, zero hist/counters/loss -------
__global__ void pre_kernel(const float* __restrict__ z, const float* __restrict__ E,
                           float* __restrict__ zsq, float* __restrict__ esq,
                           int* __restrict__ hist, float* __restrict__ loss,
                           unsigned short* __restrict__ zh,
                           unsigned short* __restrict__ eh,
                           int* __restrict__ nm, int* __restrict__ novf) {
    const int b = blockIdx.x;
    const int wave = threadIdx.x >> 6;
    const int lane = threadIdx.x & 63;
    if (b < NTOK / 4) {
        int token = b * 4 + wave;
        float4 v = ((const float4*)(z + (size_t)token * DIM))[lane];
        ushort4 h;
        h.x = __half_as_ushort(__float2half(v.x));
        h.y = __half_as_ushort(__float2half(v.y));
        h.z = __half_as_ushort(__float2half(v.z));
        h.w = __half_as_ushort(__float2half(v.w));
        *(ushort4*)(zh + (size_t)token * DIM + lane * 4) = h;
        float s = v.x * v.x + v.y * v.y + v.z * v.z + v.w * v.w;
        #pragma unroll
        for (int off = 32; off > 0; off >>= 1) s += __shfl_down(s, off);
        if (lane == 0) zsq[token] = s;
        if (b == 0 && threadIdx.x == 4) loss[0] = 0.0f;
        if (b == 0 && threadIdx.x == 5) { *nm = 0; *novf = 0; }
    } else {
        int eb = b - NTOK / 4;                 // 0..255
        int k = eb * 4 + wave;
        float4 v = ((const float4*)(E + (size_t)k * DIM))[lane];
        ushort4 h;
        h.x = __half_as_ushort(__float2half(v.x));
        h.y = __half_as_ushort(__float2half(v.y));
        h.z = __half_as_ushort(__float2half(v.z));
        h.w = __half_as_ushort(__float2half(v.w));
        *(ushort4*)(eh + (size_t)k * DIM + lane * 4) = h;
        float s = v.x * v.x + v.y * v.y + v.z * v.z + v.w * v.w;
        #pragma unroll
        for (int off = 32; off > 0; off >>= 1) s += __shfl_down(s, off);
        if (lane == 0) esq[k] = s;
        if (threadIdx.x < 4) hist[eb * 4 + threadIdx.x] = 0;
    }
}

// ---------------- f16 MFMA distance screen (token-owner, r11 restructure) ----
// One block OWNS 64 tokens. 4 chunks of 256 codes; per chunk 8 kt-steps.
// Wave = 64-code col-quarter, all 64 rows: acc[4][4], 8 frag-reads -> 16 MFMA
// (512 B LDS-read per MFMA, vs 768 in r11). B double-buffered: per kt
// {issue next loads -> frag-read buf[cur] -> MFMA -> write buf[cur^1] ->
// ONE barrier} — global latency hides under reads+MFMA; barriers 128 -> ~40.
// Bank-conflict-free strides: Als rows 260 us (520 B = 2 words mod 32 ->
// per-quarter 16 distinct starts spaced 2 -> exactly 2 words/bank); Bls rows
// 36 us (72 B = 18 words mod 32, same property). r11 had 5.25M conflicts.
__global__ __launch_bounds__(256) void dist_mfma_kernel(
        const unsigned short* __restrict__ zh, const unsigned short* __restrict__ eh,
        const float* __restrict__ esq,
        float* __restrict__ Mg, int* __restrict__ ccount,
        unsigned long long* __restrict__ cand) {
    __shared__ unsigned short Als[64 * 260];     // 33280 B
    __shared__ unsigned short Bls[2][256 * 36];  // 2 x 18432 B
    __shared__ float scr[64][4];
    __shared__ float runmin[64];
    __shared__ int lcnt[64];

    const int tid = threadIdx.x;
    const int wn = tid >> 6;                 // wave -> 64-code col quarter
    const int lane = tid & 63;
    const int l15 = lane & 15, l4 = lane >> 4;
    const int tok0 = blockIdx.x * 64;

    // stage A once: 64 rows x 256 cols = 2048 f16x8 chunks, 8 per thread
    #pragma unroll
    for (int q = 0; q < 8; ++q) {
        int c = tid + 256 * q;               // 0..2047
        int row = c >> 5, ch = c & 31;
        *(f16x8*)(Als + row * 260 + ch * 8) =
            *(const f16x8*)(zh + (size_t)(tok0 + row) * 256 + ch * 8);
    }
    if (tid < 64) { runmin[tid] = 3.4e38f; lcnt[tid] = 0; }

    // B staging coords: thread covers rows brow+64q (q=0..3) at 16B col bch
    const int brow = tid >> 2, bch = tid & 3;

    // prologue: stage B(chunk0, kt0) into buf 0
    #pragma unroll
    for (int q = 0; q < 4; ++q) {
        f16x8 r = *(const f16x8*)(eh + (size_t)(brow + 64 * q) * 256 + bch * 8);
        *(f16x8*)(Bls[0] + (brow + 64 * q) * 36 + bch * 8) = r;
    }
    __syncthreads();

    int cur = 0;
    for (int c0 = 0; c0 < KCODES; c0 += 256) {
        f32x4 acc[4][4];
        #pragma unroll
        for (int i = 0; i < 4; ++i)
            #pragma unroll
            for (int j = 0; j < 4; ++j)
                acc[i][j] = (f32x4){0.f, 0.f, 0.f, 0.f};

        for (int kt = 0; kt < 8; ++kt) {
            int nc0 = c0, nkt = kt + 1;
            if (nkt == 8) { nkt = 0; nc0 += 256; }
            const bool hasnext = (nc0 < KCODES);
            f16x8 rn[4];
            if (hasnext) {
                #pragma unroll
                for (int q = 0; q < 4; ++q)
                    rn[q] = *(const f16x8*)(
                        eh + (size_t)(nc0 + brow + 64 * q) * 256 + nkt * 32 + bch * 8);
            }
            f16x8 av[4], bv[4];
            #pragma unroll
            for (int i = 0; i < 4; ++i)
                av[i] = *(const f16x8*)(Als + (i * 16 + l15) * 260 + kt * 32 + l4 * 8);
            #pragma unroll
            for (int j = 0; j < 4; ++j)
                bv[j] = *(const f16x8*)(Bls[cur] + (wn * 64 + j * 16 + l15) * 36 + l4 * 8);
            #pragma unroll
            for (int i = 0; i < 4; ++i)
                #pragma unroll
                for (int j = 0; j < 4; ++j)
                    acc[i][j] = __builtin_amdgcn_mfma_f32_16x16x32_f16(
                        av[i], bv[j], acc[i][j], 0, 0, 0);
            if (hasnext) {
                #pragma unroll
                for (int q = 0; q < 4; ++q)
                    *(f16x8*)(Bls[cur ^ 1] + (brow + 64 * q) * 36 + bch * 8) = rn[q];
            }
            __syncthreads();                 // one barrier per kt-step
            cur ^= 1;
        }

        // chunk epilogue: per-row min over 256 cols; runmin; window emit
        float sq[4];
        #pragma unroll
        for (int j = 0; j < 4; ++j) sq[j] = esq[c0 + wn * 64 + j * 16 + l15];

        #pragma unroll
        for (int i = 0; i < 4; ++i) {
            #pragma unroll
            for (int r = 0; r < 4; ++r) {
                float v = fminf(fminf(sq[0] - 2.0f * acc[i][0][r],
                                      sq[1] - 2.0f * acc[i][1][r]),
                                fminf(sq[2] - 2.0f * acc[i][2][r],
                                      sq[3] - 2.0f * acc[i][3][r]));
                #pragma unroll
                for (int m = 1; m < 16; m <<= 1)
                    v = fminf(v, __shfl_xor(v, m));
                if (l15 == 0) scr[i * 16 + l4 * 4 + r][wn] = v;
            }
        }
        __syncthreads();
        if (tid < 64) {
            float m = fminf(fminf(scr[tid][0], scr[tid][1]),
                            fminf(scr[tid][2], scr[tid][3]));
            runmin[tid] = fminf(runmin[tid], m);
        }
        __syncthreads();
        #pragma unroll
        for (int i = 0; i < 4; ++i) {
            #pragma unroll
            for (int r = 0; r < 4; ++r) {
                const int row = i * 16 + l4 * 4 + r;
                const float thr = runmin[row] + THETA_F;
                #pragma unroll
                for (int j = 0; j < 4; ++j) {
                    float d = sq[j] - 2.0f * acc[i][j][r];
                    if (d <= thr) {
                        int slot = atomicAdd(&lcnt[row], 1);
                        if (slot < CAND_CAP)
                            cand[(size_t)slot * NTOK + tok0 + row] =
                                (((unsigned long long)__float_as_uint(d)) << 32) |
                                (unsigned)(c0 + wn * 64 + j * 16 + l15);
                    }
                }
            }
        }
    }
    __syncthreads();    // all emits / lcnt atomics done
    if (tid < 64) {
        Mg[tok0 + tid] = runmin[tid];
        ccount[tok0 + tid] = lcnt[tid];
    }
}

// ------- recheck_a: per-TOKEN filter at Mt + THETA_F --------------------
// nsurv==1 -> PROVABLY the serial-order argmin -> write idx directly (~76%).
// 2..8 -> mlist; overflow/weird -> ovf. Block-aggregated reservation: ONE
// atomicAdd(nm) + ONE atomicAdd(novf) per block.
__global__ __launch_bounds__(256) void recheck_a_kernel(
        const float* __restrict__ Mg, const int* __restrict__ ccount,
        const unsigned long long* __restrict__ cand,
        unsigned int* __restrict__ idx,
        int* __restrict__ mlist, int* __restrict__ nm,
        int* __restrict__ ovf, int* __restrict__ novf) {
    __shared__ int ps[256];
    __shared__ int base_m, base_o;
    const int tid = threadIdx.x;
    const int token = blockIdx.x * 256 + tid;
    const int cnt = ccount[token];
    const float thr = Mg[token] + THETA_F;

    const bool isovf_cap = (cnt > CAND_CAP);
    int nsurv = 0;
    int firstcode = 0;
    if (!isovf_cap) {
        for (int s = 0; s < cnt; ++s) {
            unsigned long long e = cand[(size_t)s * NTOK + token];
            float dt = __uint_as_float((unsigned)(e >> 32));
            if (dt <= thr) {
                ++nsurv;
                if (nsurv == 1) firstcode = (int)(unsigned)(e & 0x3FFull);
            }
        }
    }
    const bool ismulti = !isovf_cap && nsurv >= 2 && nsurv <= 8;
    const bool isovf = isovf_cap || (!isovf_cap && (nsurv == 0 || nsurv > 8));
    const int want = (ismulti ? 1 : 0) | ((isovf ? 1 : 0) << 16);

    ps[tid] = want;
    __syncthreads();
    #pragma unroll
    for (int off = 1; off < 256; off <<= 1) {
        int v = (tid >= off) ? ps[tid - off] : 0;
        __syncthreads();
        ps[tid] += v;
        __syncthreads();
    }
    if (tid == 255) {
        int tot = ps[255];
        base_m = (tot & 0xFFFF) ? atomicAdd(nm, tot & 0xFFFF) : 0;
        base_o = (tot >> 16) ? atomicAdd(novf, tot >> 16) : 0;
    }
    __syncthreads();
    const int off_m = (ps[tid] - want) & 0xFFFF;
    const int off_o = (ps[tid] - want) >> 16;

    if (!isovf_cap && nsurv == 1) idx[token] = (unsigned)firstcode;
    if (ismulti) mlist[base_m + off_m] = token;
    if (isovf)   ovf[base_o + off_o] = token;
}

// ------- recheck_b: wave per multi-survivor token (nsurv in [2,8]) -------
#define RB_BLOCKS 1024
__global__ __launch_bounds__(256) void recheck_b_kernel(
        const float* __restrict__ z, const float* __restrict__ E,
        const float* __restrict__ zsq, const float* __restrict__ esq,
        const float* __restrict__ Mg, const int* __restrict__ ccount,
        const unsigned long long* __restrict__ cand,
        const int* __restrict__ mlist, const int* __restrict__ nm,
        const int* __restrict__ ovf, const int* __restrict__ novf,
        unsigned int* __restrict__ idx) {
    const int wave = threadIdx.x >> 6, lane = threadIdx.x & 63;
    const int gw = blockIdx.x * 4 + wave;
    const int n = *nm;
    for (int m = gw; m < n; m += RB_BLOCKS * 4) {
        const int token = mlist[m];
        const int cnt = ccount[token];         // <= 16
        const float thr = Mg[token] + THETA_F;
        const float An = zsq[token];
        const float4 zv = *(const float4*)(z + (size_t)token * DIM + lane * 4);
        unsigned long long e = 0x7F80000000000000ull;   // dt=+inf -> filtered
        if (lane < cnt) e = cand[(size_t)lane * NTOK + token];
        const float dt = __uint_as_float((unsigned)(e >> 32));
        const int ec = (int)(unsigned)(e & 0x3FFull);
        const unsigned long long bm0 = __ballot(lane < cnt && dt <= thr);
        unsigned long long bm = bm0;
        const int ns = __popcll(bm0);          // 2..8 (recheck_a guarantee)

        float m1 = 3.4e38f, m2 = 3.4e38f; int a1 = 0x7fffffff;
        int mycode = 0; float mydv = 3.4e38f;
        #pragma unroll
        for (int i = 0; i < 8; ++i) {
            if (i < ns) {
                const int s = __ffsll(bm) - 1; bm &= bm - 1;
                const int code = __shfl(ec, s);
                const float4 ev = *(const float4*)(E + (size_t)code * DIM + lane * 4);
                float p = fmaf(zv.x, ev.x, 0.0f);
                p = fmaf(zv.y, ev.y, p);
                p = fmaf(zv.z, ev.z, p);
                p = fmaf(zv.w, ev.w, p);
                #pragma unroll
                for (int o = 1; o < 64; o <<= 1) p += __shfl_xor(p, o);
                const float dv = (An + esq[code]) - 2.0f * p;
                if (dv < m1 || (dv == m1 && code < a1)) { m2 = m1; m1 = dv; a1 = code; }
                else if (dv < m2) m2 = dv;
                if (lane == i) { mycode = code; mydv = dv; }
            }
        }
        if (m2 - m1 > 2.0f * EPSC) {
            if (lane == 0) idx[token] = (unsigned)a1;
        } else {
            // ambiguous: bit-exact serial chains for codes within 2*EPSC of m1
            float b1 = 3.4e38f; int ai = 0x7fffffff;
            for (int s = 0; s < ns; ++s) {
                const int code = __shfl(mycode, s);
                const float dvp = __shfl(mydv, s);
                if (dvp <= m1 + 2.0f * EPSC && lane == 0) {
                    const float4* zp = (const float4*)(z + (size_t)token * DIM);
                    const float4* ep = (const float4*)(E + (size_t)code * DIM);
                    float acc = 0.0f;
                    #pragma unroll 8
                    for (int q = 0; q < 64; ++q) {
                        float4 a = zp[q], b = ep[q];
                        acc = fmaf(a.x, b.x, acc); acc = fmaf(a.y, b.y, acc);
                        acc = fmaf(a.z, b.z, acc); acc = fmaf(a.w, b.w, acc);
                    }
                    float dv = (An + esq[code]) - 2.0f * acc;
                    if (dv < b1 || (dv == b1 && code < ai)) { b1 = dv; ai = code; }
                }
            }
            if (lane == 0) idx[token] = (unsigned)ai;
        }
    }
    // overflow tokens (expected ~0): wave-per-token full exact serial scan
    const int nov = *novf;
    for (int w = gw; w < nov; w += RB_BLOCKS * 4) {
        const int token = ovf[w];
        const float An = zsq[token];
        const float4* zp = (const float4*)(z + (size_t)token * DIM);
        float best = 3.4e38f; int bid = 0x7fffffff;
        for (int code = lane; code < KCODES; code += 64) {
            const float4* ep = (const float4*)(E + (size_t)code * DIM);
            float acc = 0.0f;
            for (int q = 0; q < 64; ++q) {
                float4 a = zp[q], b = ep[q];
                acc = fmaf(a.x, b.x, acc); acc = fmaf(a.y, b.y, acc);
                acc = fmaf(a.z, b.z, acc); acc = fmaf(a.w, b.w, acc);
            }
            float dv = (An + esq[code]) - 2.0f * acc;
            if (dv < best || (dv == best && code < bid)) { best = dv; bid = code; }
        }
        #pragma unroll
        for (int mm = 1; mm < 64; mm <<= 1) {
            float ov = __shfl_xor(best, mm); int oi = __shfl_xor(bid, mm);
            if (ov < best || (ov == best && oi < bid)) { best = ov; bid = oi; }
        }
        if (lane == 0) idx[token] = (unsigned)bid;
    }
}

// ------- mid: hist, quant gather, loss PARTIAL (no same-address atomic) ----
__global__ __launch_bounds__(256) void mid_kernel(
        const float* __restrict__ z, const float* __restrict__ E,
        const unsigned int* __restrict__ idxarr,
        float* __restrict__ idx_out, int* __restrict__ hist,
        float* __restrict__ quant, float* __restrict__ lpart) {
    __shared__ float ls[4];
    const int wave = threadIdx.x >> 6;
    const int lane = threadIdx.x & 63;
    const int token = blockIdx.x * 4 + wave;
    const int idx = (int)idxarr[token];

    if (lane == 0) {
        idx_out[token] = (float)idx;
        atomicAdd(&hist[idx], 1);
    }

    const float4 ev = *(const float4*)(E + (size_t)idx * DIM + lane * 4);
    const float4 zv = *(const float4*)(z + (size_t)token * DIM + lane * 4);
    *(float4*)(quant + (size_t)token * DIM + lane * 4) = ev;

    float dx = zv.x - ev.x, dy = zv.y - ev.y, dz = zv.z - ev.z, dww = zv.w - ev.w;
    float l = dx * dx + dy * dy + dz * dz + dww * dww;
    #pragma unroll
    for (int off = 32; off > 0; off >>= 1) l += __shfl_down(l, off);
    if (lane == 0) ls[wave] = l;
    __syncthreads();
    if (threadIdx.x == 0)
        lpart[blockIdx.x] = (ls[0] + ls[1]) + (ls[2] + ls[3]);
}

// ------- cs: cluster-size normalize + hist prefix-sum + loss reduce -------
__global__ __launch_bounds__(256) void cs_kernel(
        const int* __restrict__ hist, const float* __restrict__ ema_cs,
        float* __restrict__ cs_out, int* __restrict__ offs,
        int* __restrict__ cursor, const float* __restrict__ lpart,
        float* __restrict__ loss) {
    __shared__ float f[256];
    __shared__ int hs[256];
    const int tid = threadIdx.x;
    float pre4[4]; int h4[4];
    float part = 0.0f; int hp = 0;
    #pragma unroll
    for (int q = 0; q < 4; ++q) {
        int k = tid * 4 + q;
        h4[q] = hist[k];
        pre4[q] = ema_cs[k] * DECAY + (1.0f - DECAY) * (float)h4[q];
        part += pre4[q];
        hp += h4[q];
    }
    f[tid] = part; hs[tid] = hp;
    __syncthreads();
    #pragma unroll
    for (int off = 1; off < 256; off <<= 1) {
        int v = (tid >= off) ? hs[tid - off] : 0;
        __syncthreads();
        hs[tid] += v;
        __syncthreads();
    }
    int run = hs[tid] - hp;                 // exclusive base for this thread
    #pragma unroll
    for (int q = 0; q < 4; ++q) {
        int k = tid * 4 + q;
        offs[k] = run; cursor[k] = run;
        run += h4[q];
    }
    if (tid == 255) offs[KCODES] = run;     // = NTOK
    for (int s = 128; s > 0; s >>= 1) {
        if (tid < s) f[tid] += f[tid + s];
        __syncthreads();
    }
    float n = f[0];
    #pragma unroll
    for (int q = 0; q < 4; ++q) {
        int k = tid * 4 + q;
        cs_out[k] = (pre4[q] + EPSILON) / (n + KCODES * EPSILON) * n;
    }
    // ---- loss: reduce the 8192 per-block partials (coalesced) ----
    float lp = 0.0f;
    #pragma unroll
    for (int q = 0; q < 32; ++q) lp += lpart[tid + 256 * q];
    __syncthreads();
    f[tid] = lp;
    __syncthreads();
    for (int s = 128; s > 0; s >>= 1) {
        if (tid < s) f[tid] += f[tid + s];
        __syncthreads();
    }
    if (tid == 0) loss[0] = f[0];
}

// ------- scatter: counting-sort tokens into per-code buckets -------
__global__ __launch_bounds__(256) void scatter_kernel(
        const unsigned int* __restrict__ idxarr,
        int* __restrict__ cursor, int* __restrict__ tlist) {
    const int t = blockIdx.x * 256 + threadIdx.x;
    const int idx = (int)idxarr[t];
    const int pos = atomicAdd(&cursor[idx], 1);
    tlist[pos] = t;
}

// ------- fin_gather: dw[k] = sum of z rows assigned to code k -------
__global__ __launch_bounds__(256) void fin_gather_kernel(
        const float* __restrict__ z, const int* __restrict__ offs,
        const int* __restrict__ tlist, float* __restrict__ dw) {
    __shared__ float4 red[4][64];
    const int k = blockIdx.x;
    const int grp = threadIdx.x >> 6;
    const int lane = threadIdx.x & 63;
    const int s = offs[k], e = offs[k + 1];
    float4 acc = {0.f, 0.f, 0.f, 0.f};
    for (int i = s + grp; i < e; i += 4) {
        const int t = tlist[i];
        const float4 v = *(const float4*)(z + (size_t)t * DIM + lane * 4);
        acc.x += v.x; acc.y += v.y; acc.z += v.z; acc.w += v.w;
    }
    red[grp][lane] = acc;
    __syncthreads();
    if (grp == 0) {
        float4 a = red[0][lane], b = red[1][lane];
        float4 c = red[2][lane], d = red[3][lane];
        float4 o;
        o.x = (a.x + b.x) + (c.x + d.x);
        o.y = (a.y + b.y) + (c.y + d.y);
        o.z = (a.z + b.z) + (c.z + d.z);
        o.w = (a.w + b.w) + (c.w + d.w);
        *(float4*)(dw + (size_t)k * DIM + lane * 4) = o;
    }
}

// ------- fin: new_ema_w & new_embedding (+ loss finalize) -------
__global__ __launch_bounds__(256) void fin_kernel(
        const float* __restrict__ ema_w, const float* __restrict__ cs,
        float* __restrict__ emaw_inout /* holds dw */, float* __restrict__ emb_out,
        float* __restrict__ loss_inout) {
    const int i = blockIdx.x * 256 + threadIdx.x;   // f4 index, 65536 total
    const int k = i >> 6;
    float4 d = ((const float4*)emaw_inout)[i];
    float4 w = ((const float4*)ema_w)[i];
    float4 nw;
    nw.x = w.x * DECAY + (1.0f - DECAY) * d.x;
    nw.y = w.y * DECAY + (1.0f - DECAY) * d.y;
    nw.z = w.z * DECAY + (1.0f - DECAY) * d.z;
    nw.w = w.w * DECAY + (1.0f - DECAY) * d.w;
    ((float4*)emaw_inout)[i] = nw;
    float inv = 1.0f / cs[k];
    float4 e; e.x = nw.x * inv; e.y = nw.y * inv; e.z = nw.z * inv; e.w = nw.w * inv;
    ((float4*)emb_out)[i] = e;
    if (i == 0)
        loss_inout[0] = COMMITMENT_COST * loss_inout[0] / (float)((size_t)NTOK * DIM);
}

extern "C" void kernel_launch(void* const* d_in, const int* in_sizes, int n_in,
                              void* d_out, int out_size, void* d_ws, size_t ws_size,
                              hipStream_t stream) {
    const float* z      = (const float*)d_in[0];
    const float* E      = (const float*)d_in[1];
    const float* ema_cs = (const float*)d_in[2];
    const float* ema_w  = (const float*)d_in[3];
    float* out = (float*)d_out;

    float* emb = out + O_EMB;
    unsigned int* idx = (unsigned int*)(emb + SE_IDX);
    float* esq  = emb + SE_ESQ;
    float* zsq  = emb + SE_ZSQ;
    int*   hist = (int*)(emb + SE_HIST);
    int*   nm     = (int*)(emb + SE_NM);
    int*   novf   = (int*)(emb + SE_NOVF);
    int*   mlist  = (int*)(emb + SE_MLIST);
    int*   ovf    = (int*)(emb + SE_OVF);
    int*   offs   = (int*)(emb + SE_OFFS);
    int*   cursor = (int*)(emb + SE_CUR);
    int*   tlist  = (int*)(emb + SE_TLIST);
    float* lpart  = emb + SE_LPART;

    unsigned short* zh = (unsigned short*)(out + SQ_ZH);
    unsigned short* eh = (unsigned short*)(out + SQ_EH);
    float* Mg = out + SQ_MG;
    int* ccount = (int*)(out + SQ_CC);
    unsigned long long* cand = (unsigned long long*)(out + SQ_CAND);

    pre_kernel<<<NTOK / 4 + KCODES / 4, 256, 0, stream>>>(
        z, E, zsq, esq, hist, out + O_LOSS, zh, eh, nm, novf);
    dist_mfma_kernel<<<NTOK / 64, 256, 0, stream>>>(
        zh, eh, esq, Mg, ccount, cand);
    recheck_a_kernel<<<NTOK / 256, 256, 0, stream>>>(
        Mg, ccount, cand, idx, mlist, nm, ovf, novf);
    recheck_b_kernel<<<RB_BLOCKS, 256, 0, stream>>>(
        z, E, zsq, esq, Mg, ccount, cand, mlist, nm, ovf, novf, idx);
    mid_kernel<<<NTOK / 4, 256, 0, stream>>>(z, E, idx, out + O_IDX, hist,
                                             out + O_QUANT, lpart);
    cs_kernel<<<1, 256, 0, stream>>>(hist, ema_cs, out + O_CS, offs, cursor,
                                     lpart, out + O_LOSS);
    scatter_kernel<<<NTOK / 256, 256, 0, stream>>>(idx, cursor, tlist);
    fin_gather_kernel<<<KCODES, 256, 0, stream>>>(z, offs, tlist, out + O_EMAW);
    fin_kernel<<<256, 256, 0, stream>>>(ema_w, out + O_CS, out + O_EMAW, emb,
                                        out + O_LOSS);
}